// Round 12
// baseline (212.977 us; speedup 1.0000x reference)
//
#include <hip/hip_runtime.h>
#include <math.h>

// ---------------- problem constants ----------------
constexpr int N_CPGS = 20000;
constexpr int NF     = 10001;      // N/2+1
constexpr int BZ     = 4;
constexpr int NEDGE  = 320000;
constexpr int KPAD   = 10240;      // padded freq count
// FFT decomposition: n = n1 + 200*n2, n1 in [0,200), n2 in [0,100)
constexpr int FN1    = 200;
constexpr int FN2    = 100;
constexpr int HB     = NEDGE / 256;          // 1250 hist/scatter blocks
constexpr int DOTSB  = 384;                  // dots blocks (first in k_gatdots)
constexpr int GATB   = 4096;                 // GAT blocks
constexpr int NG     = 4096;                 // x-grid size (table)
constexpr int TROW   = 144;                  // table row stride (136 used, f4-pad)
constexpr int TTB    = NG / 64;              // 64 table-tile blocks
constexpr int BPB    = 79;                   // apply blocks per batch
constexpr int NODEB  = 4 * BPB;              // 316
constexpr int H0MB   = 32;                   // h0sum matmul blocks

// ---------------- workspace layout (float offsets) ----------------
constexpr size_t W_XMEAN   = 0;        // 4
constexpr size_t W_SMSTAT  = 64;       // 2
constexpr size_t W_NORMSQ  = 128;      // 4   [zeroed in k_pre]
constexpr size_t W_H0SUM   = 192;      // 256 [zeroed in k_pre]
constexpr size_t W_GATMEAN = 448;      // 256 [zeroed in k_pre]
constexpr size_t W_PREP    = 704;      // 8
constexpr size_t W_D       = 768;      // 3*128*4
constexpr size_t W_MAG     = 2304;     // BZ*NF = 40004
constexpr size_t W_SSRC    = 42368;    // float[(b*N+n)*4+h] = 320000 (per-batch)
constexpr size_t W_SDST    = 362368;   // 320000
constexpr size_t W_H       = 682368;   // bf16[(b*N+n)*64+f] = 5.12MB (per-batch)
constexpr size_t W_Y       = 5802368;  // float2[(n1*100+k2)*4+b] = 160000 floats
constexpr size_t W_TAB     = 5962368;  // NG*TROW = 589824 floats (~2.36MB)
                                       // row: [0..63] h, [64..127] h0, [128..131] s_src, [132..135] s_dst
constexpr size_t W_WEIGHT  = 9062784;  // 4*4096 grid weights [zeroed via memset]
constexpr size_t W_COUNTS  = 9079168;  // int 20000 [zeroed via memset]
constexpr size_t W_OFFS    = 9099168;  // int 20001
constexpr size_t W_CURSOR  = 9119232;  // int 20000
constexpr size_t W_SORTSRC = 9139232;  // int 320000
// end: 9459232 floats = 37,836,928 bytes

#define DEVFN static __device__ __forceinline__

// Fast gelu: A&S 7.1.26 erf, |abs err| <= 1.5e-7.
DEVFN float gelu_f(float v) {
    float ax = fabsf(v) * 0.70710678118654752440f;
    float t = 1.0f / fmaf(0.3275911f, ax, 1.0f);
    float p = fmaf(t, 1.061405429f, -1.453152027f);
    p = fmaf(p, t, 1.421413741f);
    p = fmaf(p, t, -0.284496736f);
    p = fmaf(p, t, 0.254829592f);
    p = p * t;
    float e = __expf(-ax * ax);
    float er = copysignf(fmaf(-p, e, 1.0f), v);
    return 0.5f * v * (1.0f + er);
}

DEVFN float wred_sum(float v) {
    #pragma unroll
    for (int m = 32; m; m >>= 1) v += __shfl_xor(v, m);
    return v;
}

DEVFN unsigned int bfr(float f) {            // fp32 -> bf16 bits, RNE
    unsigned int u = __float_as_uint(f);
    return (u + 0x7fffu + ((u >> 16) & 1u)) >> 16;
}
DEVFN float bf2f(unsigned short v) { return __uint_as_float(((unsigned int)v) << 16); }

// ====== L1: k_pre — stats/zeroing (0-5) + table build (6-69) + edge histogram (70+) ======
__global__ __launch_bounds__(256) void k_pre(
    const float* __restrict__ x, const float* __restrict__ ge_w,
    const float* __restrict__ ge_b, const float* __restrict__ ge_g,
    const float* __restrict__ ge_beta, const float* __restrict__ gat_w,
    const float* __restrict__ gat_attn, const float* __restrict__ fw,
    const int* __restrict__ ei, float* __restrict__ ws) {
    int bb = blockIdx.x, t = threadIdx.x;
    if (bb >= 6 + TTB) {                               // edge histogram (counts pre-zeroed)
        int e = (bb - 6 - TTB) * 256 + t;
        if (e < NEDGE) atomicAdd((int*)(ws + W_COUNTS) + ei[NEDGE + e], 1);
        return;
    }
    if (bb >= 6) {
        // ---- table tile: 64 grid points x (h, h0, scores) ----
        int g0 = (bb - 6) * 64;
        int lane = t & 63;
        // per-wave closed-form LN stats
        float wv_ = ge_w[lane], bv_ = ge_b[lane];
        float mw = wred_sum(wv_) * (1.f / 64.f);
        float mb = wred_sum(bv_) * (1.f / 64.f);
        float wc = wv_ - mw, bc = bv_ - mb;
        float A = wred_sum(wc * wc) * (1.f / 64.f);
        float C = wred_sum(wc * bc) * (1.f / 64.f);
        float Dd = wred_sum(bc * bc) * (1.f / 64.f);

        __shared__ __align__(16) float h0T[64 * 68];   // [feat j][gridpt]
        __shared__ __align__(16) float gwT[64 * 68];   // [j][i] = gat_w[i][j]
        __shared__ float xsv[64], rss[64];

        for (int idx = t; idx < 4096; idx += 256) {
            int i = idx >> 6, j = idx & 63;
            gwT[j * 68 + i] = gat_w[idx];
        }
        if (t < 64) {
            float xg = (float)(g0 + t) * (1.0f / 4095.0f);
            xsv[t] = xg;
            float var = xg * xg * A + 2.f * xg * C + Dd;
            rss[t] = 1.0f / sqrtf(var + 1e-5f);
        }
        __syncthreads();
        for (int idx = t; idx < 4096; idx += 256) {
            int j = idx >> 6, nd = idx & 63;
            float v = (xsv[nd] * (ge_w[j] - mw) + (ge_b[j] - mb)) * rss[nd];
            h0T[j * 68 + nd] = gelu_f(v * ge_g[j] + ge_beta[j]);
        }
        __syncthreads();
        // 64x64 @ 64x64 matmul, 16x16 threads, 4x4 micro-tile
        int tr = t >> 4, tc = t & 15;
        float acc[4][4] = {};
        #pragma unroll 8
        for (int j = 0; j < 64; ++j) {
            const float4 av = *(const float4*)&h0T[j * 68 + (tr << 2)];
            const float4 bv = *(const float4*)&gwT[j * 68 + (tc << 2)];
            #pragma unroll
            for (int u = 0; u < 4; ++u) {
                float a = (u == 0) ? av.x : (u == 1) ? av.y : (u == 2) ? av.z : av.w;
                acc[u][0] = fmaf(a, bv.x, acc[u][0]);
                acc[u][1] = fmaf(a, bv.y, acc[u][1]);
                acc[u][2] = fmaf(a, bv.z, acc[u][2]);
                acc[u][3] = fmaf(a, bv.w, acc[u][3]);
            }
        }
        float* tab = ws + W_TAB;
        // h features -> table
        #pragma unroll
        for (int u = 0; u < 4; ++u) {
            int gp = g0 + tr * 4 + u;
            *(float4*)&tab[(size_t)gp * TROW + tc * 4] =
                make_float4(acc[u][0], acc[u][1], acc[u][2], acc[u][3]);
        }
        // h0 -> table
        for (int idx = t; idx < 4096; idx += 256) {
            int j = idx >> 6, nd = idx & 63;
            tab[(size_t)(g0 + nd) * TROW + 64 + j] = h0T[j * 68 + nd];
        }
        // scores -> table
        {
            int hh = tc >> 2;
            float ps[4], pd[4];
            #pragma unroll
            for (int u = 0; u < 4; ++u) {
                float s = 0.f, d = 0.f;
                #pragma unroll
                for (int kk = 0; kk < 4; ++kk) {
                    float asv = gat_attn[hh * 32 + (tc & 3) * 4 + kk];
                    float adv = gat_attn[hh * 32 + 16 + (tc & 3) * 4 + kk];
                    s = fmaf(acc[u][kk], asv, s);
                    d = fmaf(acc[u][kk], adv, d);
                }
                ps[u] = s; pd[u] = d;
            }
            #pragma unroll
            for (int u = 0; u < 4; ++u) {
                ps[u] += __shfl_xor(ps[u], 1); ps[u] += __shfl_xor(ps[u], 2);
                pd[u] += __shfl_xor(pd[u], 1); pd[u] += __shfl_xor(pd[u], 2);
            }
            if ((tc & 3) == 0) {
                #pragma unroll
                for (int u = 0; u < 4; ++u) {
                    int gp = g0 + tr * 4 + u;
                    tab[(size_t)gp * TROW + 128 + hh] = ps[u];
                    tab[(size_t)gp * TROW + 132 + hh] = pd[u];
                }
            }
        }
        return;
    }
    __shared__ float sd[256];
    if (bb < 4) {
        const float4* x4 = (const float4*)(x + (size_t)bb * N_CPGS);
        float s = 0.f;
        for (int i = t; i < N_CPGS / 4; i += 256) {
            float4 v = x4[i];
            s += (v.x + v.y) + (v.z + v.w);
        }
        sd[t] = s; __syncthreads();
        for (int o = 128; o; o >>= 1) { if (t < o) sd[t] += sd[t + o]; __syncthreads(); }
        if (t == 0) ws[W_XMEAN + bb] = sd[0] * (1.0f / N_CPGS);
    } else if (bb == 4) {
        for (int i = t; i < (int)(W_PREP - W_NORMSQ); i += 256) ws[W_NORMSQ + i] = 0.f;
    } else {    // bb == 5
        float mx = -1e30f;
        for (int i = t; i < NF; i += 256) mx = fmaxf(mx, fw[i]);
        sd[t] = mx; __syncthreads();
        for (int o = 128; o; o >>= 1) { if (t < o) sd[t] = fmaxf(sd[t], sd[t + o]); __syncthreads(); }
        mx = sd[0]; __syncthreads();
        float s = 0.f;
        for (int i = t; i < NF; i += 256) s += expf(fw[i] - mx);
        sd[t] = s; __syncthreads();
        for (int o = 128; o; o >>= 1) { if (t < o) sd[t] += sd[t + o]; __syncthreads(); }
        if (t == 0) { ws[W_SMSTAT] = mx; ws[W_SMSTAT + 1] = sd[0]; }
    }
}

// ====== L2: k_node — block 0: scan; [1,1+NODEB): table-apply; rest: FFT stage 1 ======
__global__ __launch_bounds__(256) void k_node(const float* __restrict__ x,
                                              float* __restrict__ ws)
{
    int t = threadIdx.x;
    int nb = blockIdx.x;
    if (nb == 0) {                                     // exclusive scan of dst counts
        const int* cnt = (const int*)(ws + W_COUNTS);
        int* offs = (int*)(ws + W_OFFS);
        int* cur  = (int*)(ws + W_CURSOR);
        constexpr int PER = (N_CPGS + 255) / 256;      // 79
        int i0 = t * PER;
        int s = 0;
        for (int i = 0; i < PER; ++i) { int idx = i0 + i; if (idx < N_CPGS) s += cnt[idx]; }
        __shared__ int sdi[256];
        sdi[t] = s; __syncthreads();
        for (int off = 1; off < 256; off <<= 1) {
            int v = (t >= off) ? sdi[t - off] : 0;
            __syncthreads();
            sdi[t] += v;
            __syncthreads();
        }
        int run = sdi[t] - s;
        for (int i = 0; i < PER; ++i) {
            int idx = i0 + i;
            if (idx < N_CPGS) { offs[idx] = run; cur[idx] = run; run += cnt[idx]; }
        }
        if (t == 255) offs[N_CPGS] = sdi[255];
        return;
    }
    if (nb >= 1 + NODEB) {                             // FFT stage 1
        int fb = nb - 1 - NODEB;                       // 0..399
        int b = fb / 100;
        int n1base = (fb % 100) * 2;
        int n1l = t >> 7, k2 = t & 127;
        __shared__ float xs[2][100];
        float xm = ws[W_XMEAN + b];
        for (int i = t; i < 200; i += 256) {
            int nl = (i >= 100) ? 1 : 0, n2 = (i >= 100) ? i - 100 : i;
            xs[nl][n2] = x[(size_t)b * N_CPGS + n1base + nl + 200 * n2] - xm;
        }
        __syncthreads();
        int k2e = (k2 < 100) ? k2 : 0;
        constexpr float T100 = 6.2831853071795864769f / 100.f;
        float dc, dsn;
        { float sn, cn; sincosf(T100 * (float)k2e, &sn, &cn); dc = cn; dsn = -sn; }
        float yr = 0.f, yi = 0.f;
        #pragma unroll
        for (int half = 0; half < 2; ++half) {
            float c, s;
            { int m = (k2e * (half * 50)) % 100; float sn, cn; sincosf(T100 * (float)m, &sn, &cn); c = cn; s = -sn; }
            #pragma unroll 5
            for (int j = 0; j < 50; ++j) {
                float xv = xs[n1l][half * 50 + j];
                yr = fmaf(xv, c, yr); yi = fmaf(xv, s, yi);
                float tc_ = c * dc - s * dsn; s = s * dc + c * dsn; c = tc_;
            }
        }
        if (k2 < 100)
            ((float2*)(ws + W_Y))[((size_t)(n1base + n1l) * FN2 + k2) * 4 + b] = make_float2(yr, yi);
        return;
    }
    // ---- table apply: thread-per-node, no LDS/barriers/shuffles ----
    int tile = nb - 1;                                 // 0..315
    int b = tile / BPB;
    int lt = tile - b * BPB;
    int n = lt * 256 + t;
    if (n >= N_CPGS) return;
    float xv = x[(size_t)b * N_CPGS + n];
    float u = xv * 4095.0f;
    int g = (int)u;
    g = (g < 0) ? 0 : ((g > 4094) ? 4094 : g);
    float f = u - (float)g;
    const float* T0 = ws + W_TAB + (size_t)g * TROW;
    const float* T1 = T0 + TROW;
    // h features: lerp + bf16 pack
    unsigned short* hrow = (unsigned short*)(ws + W_H) + ((size_t)b * N_CPGS + n) * 64;
    #pragma unroll
    for (int q = 0; q < 16; ++q) {
        float4 a = *(const float4*)(T0 + q * 4);
        float4 c = *(const float4*)(T1 + q * 4);
        float v0 = fmaf(f, c.x - a.x, a.x);
        float v1 = fmaf(f, c.y - a.y, a.y);
        float v2 = fmaf(f, c.z - a.z, a.z);
        float v3 = fmaf(f, c.w - a.w, a.w);
        uint2 pv;
        pv.x = bfr(v0) | (bfr(v1) << 16);
        pv.y = bfr(v2) | (bfr(v3) << 16);
        *(uint2*)(hrow + q * 4) = pv;
    }
    // scores: lerp
    {
        float4 a0 = *(const float4*)(T0 + 128), c0 = *(const float4*)(T1 + 128);
        float4 a1 = *(const float4*)(T0 + 132), c1 = *(const float4*)(T1 + 132);
        *(float4*)(ws + W_SSRC + ((size_t)b * N_CPGS + n) * 4) =
            make_float4(fmaf(f, c0.x - a0.x, a0.x), fmaf(f, c0.y - a0.y, a0.y),
                        fmaf(f, c0.z - a0.z, a0.z), fmaf(f, c0.w - a0.w, a0.w));
        *(float4*)(ws + W_SDST + ((size_t)b * N_CPGS + n) * 4) =
            make_float4(fmaf(f, c1.x - a1.x, a1.x), fmaf(f, c1.y - a1.y, a1.y),
                        fmaf(f, c1.z - a1.z, a1.z), fmaf(f, c1.w - a1.w, a1.w));
    }
    // h0sum via grid weights (exactly = per-node lerp summed)
    atomicAdd(ws + W_WEIGHT + (size_t)b * NG + g, 1.0f - f);
    atomicAdd(ws + W_WEIGHT + (size_t)b * NG + g + 1, f);
}

// == L3: k_scat2 — [0,HB): scatter; [HB,HB+160): fft2+mag+norms; [HB+160,+32): h0sum mm ==
__global__ __launch_bounds__(256) void k_scat2(const int* __restrict__ ei,
                                               float* __restrict__ ws) {
    int t = threadIdx.x;
    if (blockIdx.x < HB) {
        int e = blockIdx.x * 256 + t;
        if (e < NEDGE) {
            int s = ei[e], d = ei[NEDGE + e];
            int pos = atomicAdd((int*)(ws + W_CURSOR) + d, 1);
            ((int*)(ws + W_SORTSRC))[pos] = s;
        }
        return;
    }
    if (blockIdx.x >= HB + 160) {
        // h0sum[b][j] = sum_g weight[b][g] * T_h0[g][j]
        int hb = blockIdx.x - HB - 160;                // 0..31
        int b = t >> 6, j = t & 63;
        const float* wgt = ws + W_WEIGHT + (size_t)b * NG;
        const float* tab = ws + W_TAB;
        float acc = 0.f;
        int gbeg = hb * (NG / H0MB), gend = gbeg + NG / H0MB;
        for (int g = gbeg; g < gend; ++g)
            acc = fmaf(wgt[g], tab[(size_t)g * TROW + 64 + j], acc);
        atomicAdd(ws + W_H0SUM + b * 64 + j, acc);
        return;
    }
    // FFT stage 2, full 200-term sum per thread: gid -> (k, b)
    int gid = (blockIdx.x - HB) * 256 + t;             // 0..40959
    int k = gid >> 2, b = gid & 3;                     // k < KPAD
    int k2 = k % 100;
    const float2* Y2 = (const float2*)(ws + W_Y);
    constexpr float W0 = 6.2831853071795864769f / 20000.f;
    float dc, dsn;
    { float sn, cn; sincosf(W0 * (float)k, &sn, &cn); dc = cn; dsn = -sn; }
    float xr = 0.f, xi = 0.f;
    #pragma unroll
    for (int seg = 0; seg < 4; ++seg) {
        int n1b = seg * 50;
        float c, s;
        { int m = (k * n1b) % 20000; float sn, cn; sincosf(W0 * (float)m, &sn, &cn); c = cn; s = -sn; }
        #pragma unroll 5
        for (int j = 0; j < 50; ++j) {
            float2 y = Y2[((size_t)(n1b + j) * FN2 + k2) * 4 + b];
            xr = fmaf(y.x, c, xr); xr = fmaf(-y.y, s, xr);
            xi = fmaf(y.x, s, xi); xi = fmaf( y.y, c, xi);
            float tc_ = c * dc - s * dsn; s = s * dc + c * dsn; c = tc_;
        }
    }
    bool ok = k < NF;
    float m = 0.f;
    if (ok) {
        m = log1pf(sqrtf(xr * xr + xi * xi));
        ws[W_MAG + (size_t)b * NF + k] = m;
    }
    float msq = ok ? m * m : 0.f;
    #pragma unroll
    for (int o = 4; o < 64; o <<= 1) msq += __shfl_xor(msq, o);   // sum over same-b lanes
    if ((t & 63) < 4) atomicAdd(ws + W_NORMSQ + b, msq);
}

// ======== L4: k_gatdots — [0,DOTSB): dots; [DOTSB,DOTSB+GATB): GAT ====
__global__ __launch_bounds__(256) void k_gatdots(
    const float* __restrict__ fftw1, const float* __restrict__ plW,
    const float* __restrict__ plalpha, const float* __restrict__ fw,
    float* __restrict__ ws)
{
    int t = threadIdx.x;
    if (blockIdx.x >= DOTSB) {
        int g = blockIdx.x - DOTSB;                    // 0..4095
        int xcd = g & 7;
        int b = xcd >> 1;                              // batch pinned to 2 XCDs
        int blk = ((g >> 3) << 1) | (xcd & 1);         // 0..1023
        int w = t >> 6, lane = t & 63;
        int wv = blk * 4 + w;                          // 0..4095
        int egrp = lane >> 4, fgrp = lane & 15;
        int hh = fgrp >> 2;
        const int* offs = (const int*)(ws + W_OFFS);
        const int* ssrt = (const int*)(ws + W_SORTSRC);
        const float4* s4src = (const float4*)(ws + W_SSRC);
        const float4* s4dst = (const float4*)(ws + W_SDST);
        const uint2* hbp = (const uint2*)(ws + W_H);
        size_t bN = (size_t)b * N_CPGS;
        float gacc0 = 0.f, gacc1 = 0.f, gacc2 = 0.f, gacc3 = 0.f;

        __shared__ float elds[4][4][68];               // [wave][head][edge]
        __shared__ int   slds[4][68];
        __shared__ float gred[4][64];

        for (int dst = wv; dst < N_CPGS; dst += GATB) {
            int o0 = offs[dst], o1 = offs[dst + 1];
            if (o0 == o1) continue;                    // gelu(0) = 0
            float4 sd4 = s4dst[bN + dst];
            float es = 0.f;
            float a0 = 0.f, a1 = 0.f, a2 = 0.f, a3 = 0.f;
            for (int c0 = o0; c0 < o1; c0 += 64) {
                int cnt = min(64, o1 - c0);
                float v0 = 0.f, v1 = 0.f, v2 = 0.f, v3 = 0.f;
                int s = 0;
                if (lane < cnt) {
                    s = ssrt[c0 + lane];
                    float4 ss = s4src[bN + s];
                    v0 = ss.x + sd4.x; v0 = (v0 >= 0.f) ? v0 : 0.2f * v0; v0 = __expf(v0);
                    v1 = ss.y + sd4.y; v1 = (v1 >= 0.f) ? v1 : 0.2f * v1; v1 = __expf(v1);
                    v2 = ss.z + sd4.z; v2 = (v2 >= 0.f) ? v2 : 0.2f * v2; v2 = __expf(v2);
                    v3 = ss.w + sd4.w; v3 = (v3 >= 0.f) ? v3 : 0.2f * v3; v3 = __expf(v3);
                }
                slds[w][lane] = s;
                elds[w][0][lane] = v0; elds[w][1][lane] = v1;
                elds[w][2][lane] = v2; elds[w][3][lane] = v3;
                int niter = (cnt + 3) >> 2;
                for (int i = 0; i < niter; ++i) {
                    int j = (i << 2) + egrp;
                    float e = elds[w][hh][j];
                    int sj = slds[w][j];
                    uint2 hv = hbp[(bN + sj) * 16 + fgrp];
                    es += e;
                    a0 = fmaf(e, bf2f((unsigned short)(hv.x & 0xffffu)), a0);
                    a1 = fmaf(e, bf2f((unsigned short)(hv.x >> 16)),     a1);
                    a2 = fmaf(e, bf2f((unsigned short)(hv.y & 0xffffu)), a2);
                    a3 = fmaf(e, bf2f((unsigned short)(hv.y >> 16)),     a3);
                }
            }
            es += __shfl_xor(es, 16); es += __shfl_xor(es, 32);
            a0 += __shfl_xor(a0, 16); a0 += __shfl_xor(a0, 32);
            a1 += __shfl_xor(a1, 16); a1 += __shfl_xor(a1, 32);
            a2 += __shfl_xor(a2, 16); a2 += __shfl_xor(a2, 32);
            a3 += __shfl_xor(a3, 16); a3 += __shfl_xor(a3, 32);
            float inv = 1.f / (es + 1e-8f);
            gacc0 += gelu_f(a0 * inv); gacc1 += gelu_f(a1 * inv);
            gacc2 += gelu_f(a2 * inv); gacc3 += gelu_f(a3 * inv);
        }
        if (egrp == 0) {
            gred[w][fgrp * 4 + 0] = gacc0; gred[w][fgrp * 4 + 1] = gacc1;
            gred[w][fgrp * 4 + 2] = gacc2; gred[w][fgrp * 4 + 3] = gacc3;
        }
        __syncthreads();
        if (t < 64)
            atomicAdd(ws + W_GATMEAN + b * 64 + t, gred[0][t] + gred[1][t] + gred[2][t] + gred[3][t]);
        return;
    }
    // ---- dots (blocks 0..383) ----
    int bb2 = blockIdx.x;
    int m = bb2 >> 7;
    int r = bb2 & 127;
    const float* mag = ws + W_MAG;
    float smx = ws[W_SMSTAT], ssm = ws[W_SMSTAT + 1];
    float sc_fw = (float)NF / ssm;
    float inv_n0 = 1.f / (sqrtf(ws[W_NORMSQ + 0]) + 1e-8f);
    float inv_n1 = 1.f / (sqrtf(ws[W_NORMSQ + 1]) + 1e-8f);
    float inv_n2 = 1.f / (sqrtf(ws[W_NORMSQ + 2]) + 1e-8f);
    float inv_n3 = 1.f / (sqrtf(ws[W_NORMSQ + 3]) + 1e-8f);
    const float* row = ((m == 0) ? fftw1 : (m == 1) ? plW : plalpha) + (size_t)r * NF;
    float a0 = 0.f, a1 = 0.f, a2 = 0.f, a3 = 0.f;
    for (int k = t; k < NF; k += 256) {
        float wv = row[k];
        float g0 = mag[k], g1 = mag[NF + k], g2 = mag[2 * NF + k], g3 = mag[3 * NF + k];
        if (m == 0) {
            float s = expf(fw[k] - smx) * sc_fw;
            wv *= s;
            a0 = fmaf(wv, g0, a0); a1 = fmaf(wv, g1, a1); a2 = fmaf(wv, g2, a2); a3 = fmaf(wv, g3, a3);
        } else if (m == 1) {
            a0 = fmaf(wv, g0, a0); a1 = fmaf(wv, g1, a1); a2 = fmaf(wv, g2, a2); a3 = fmaf(wv, g3, a3);
        } else {
            wv = 1.f / (1.f + expf(-wv));   // sigmoid(pl_alpha)
            a0 = fmaf(wv, g0 * g0 * inv_n0, a0); a1 = fmaf(wv, g1 * g1 * inv_n1, a1);
            a2 = fmaf(wv, g2 * g2 * inv_n2, a2); a3 = fmaf(wv, g3 * g3 * inv_n3, a3);
        }
    }
    __shared__ float sd[256];
    float acc[4] = {a0, a1, a2, a3};
    #pragma unroll
    for (int bb = 0; bb < 4; ++bb) {
        sd[t] = acc[bb]; __syncthreads();
        for (int o = 128; o; o >>= 1) { if (t < o) sd[t] += sd[t + o]; __syncthreads(); }
        if (t == 0) ws[W_D + ((size_t)m * 128 + r) * 4 + bb] = sd[0];
        __syncthreads();
    }
}

// ================= L5: k_final =================
DEVFN float ln64(float v, const float* g, const float* bt, int lane) {
    float mn = wred_sum(v) * (1.f / 64.f);
    float d = v - mn;
    float var = wred_sum(d * d) * (1.f / 64.f);
    return d * (1.0f / sqrtf(var + 1e-5f)) * g[lane] + bt[lane];
}
DEVFN void ln128(float& v0, float& v1, const float* g, const float* bt, int lane) {
    float mn = wred_sum(v0 + v1) * (1.f / 128.f);
    float d0 = v0 - mn, d1 = v1 - mn;
    float var = wred_sum(d0 * d0 + d1 * d1) * (1.f / 128.f);
    float rs = 1.0f / sqrtf(var + 1e-5f);
    v0 = d0 * rs * g[lane] + bt[lane];
    v1 = d1 * rs * g[lane + 64] + bt[lane + 64];
}
DEVFN float dotW128(const float* __restrict__ W, const float* __restrict__ v, int c) {
    const float4* w4 = (const float4*)(W + (size_t)c * 128);
    float acc = 0.f;
    #pragma unroll
    for (int q = 0; q < 32; ++q) {
        float4 wv = w4[q];
        const float* vv = v + q * 4;
        acc = fmaf(wv.x, vv[0], acc); acc = fmaf(wv.y, vv[1], acc);
        acc = fmaf(wv.z, vv[2], acc); acc = fmaf(wv.w, vv[3], acc);
    }
    return acc;
}
DEVFN float dotW64(const float* __restrict__ W, const float* __restrict__ v, int c) {
    const float4* w4 = (const float4*)(W + (size_t)c * 64);
    float acc = 0.f;
    #pragma unroll
    for (int q = 0; q < 16; ++q) {
        float4 wv = w4[q];
        const float* vv = v + q * 4;
        acc = fmaf(wv.x, vv[0], acc); acc = fmaf(wv.y, vv[1], acc);
        acc = fmaf(wv.z, vv[2], acc); acc = fmaf(wv.w, vv[3], acc);
    }
    return acc;
}

__global__ __launch_bounds__(256) void k_final(
    const float* __restrict__ fft_b1, const float* __restrict__ fft_ln1_g, const float* __restrict__ fft_ln1_b,
    const float* __restrict__ fft_w2, const float* __restrict__ fft_b2,
    const float* __restrict__ fft_ln2_g, const float* __restrict__ fft_ln2_b,
    const float* __restrict__ gp_w, const float* __restrict__ gp_b,
    const float* __restrict__ gp_ln_g, const float* __restrict__ gp_ln_b,
    const float* __restrict__ pl_eta, const float* __restrict__ pl_bias,
    const float* __restrict__ pn_g, const float* __restrict__ pn_b,
    const float* __restrict__ pp_w, const float* __restrict__ pp_b,
    const float* __restrict__ pp_ln_g, const float* __restrict__ pp_ln_b,
    const float* __restrict__ gate_w1, const float* __restrict__ gate_b1,
    const float* __restrict__ gate_w2, const float* __restrict__ gate_b2,
    const float* __restrict__ head_w1, const float* __restrict__ head_b1,
    const float* __restrict__ head_w2, const float* __restrict__ head_b2,
    float* __restrict__ ws, float* __restrict__ out)
{
    int t = threadIdx.x, b = t >> 6, lane = t & 63;
    __shared__ float vlds[4][256];
    float* vb = vlds[b];
    const float* D = ws + W_D;
    int r0 = lane, r1 = lane + 64;

    float f0 = D[(0 * 128 + r0) * 4 + b] + fft_b1[r0];
    float f1 = D[(0 * 128 + r1) * 4 + b] + fft_b1[r1];
    ln128(f0, f1, fft_ln1_g, fft_ln1_b, lane);
    vb[lane] = gelu_f(f0); vb[64 + lane] = gelu_f(f1);
    float catf = ln64(dotW128(fft_w2, vb, lane) + fft_b2[lane], fft_ln2_g, fft_ln2_b, lane);

    float hgm = (ws[W_H0SUM + b * 64 + lane] + ws[W_GATMEAN + b * 64 + lane]) * (1.f / N_CPGS);
    vb[lane] = hgm;
    float catg = ln64(dotW64(gp_w, vb, lane) + gp_b[lane], gp_ln_g, gp_ln_b, lane);

    float eta = pl_eta[0];
    float ys0 = D[(1 * 128 + r0) * 4 + b] + pl_bias[r0];
    float ys1 = D[(1 * 128 + r1) * 4 + b] + pl_bias[r1];
    float q0 = D[(2 * 128 + r0) * 4 + b];
    float q1 = D[(2 * 128 + r1) * 4 + b];
    float u0 = gelu_f(ys0 + eta * tanhf(ys0) * q0);
    float u1 = gelu_f(ys1 + eta * tanhf(ys1) * q1);
    ln128(u0, u1, pn_g, pn_b, lane);
    vb[lane] = u0; vb[64 + lane] = u1;
    float catp = ln64(dotW128(pp_w, vb, lane) + pp_b[lane], pp_ln_g, pp_ln_b, lane);

    vb[lane] = catf; vb[64 + lane] = catg; vb[128 + lane] = catp;
    if (lane < 6) {
        float a = gate_b1[lane];
        const float* wrow = gate_w1 + lane * 192;
        #pragma unroll 4
        for (int j = 0; j < 192; ++j) a = fmaf(wrow[j], vb[j], a);
        vb[192 + lane] = gelu_f(a);
    }
    float gv[3];
    #pragma unroll
    for (int c = 0; c < 3; ++c) {
        float a = gate_b2[c];
        #pragma unroll
        for (int j = 0; j < 6; ++j) a = fmaf(gate_w2[c * 6 + j], vb[192 + j], a);
        gv[c] = a;
    }
    float gmx = fmaxf(gv[0], fmaxf(gv[1], gv[2]));
    float e0 = expf(gv[0] - gmx), e1 = expf(gv[1] - gmx), e2 = expf(gv[2] - gmx);
    float inv = 1.f / (e0 + e1 + e2);
    float fus = catf * (e0 * inv) + catg * (e1 * inv) + catp * (e2 * inv);

    vb[lane] = fus;
    float hval = 0.f;
    if (lane < 32) {
        float a = dotW64(head_w1, vb, lane) + head_b1[lane];
        hval = gelu_f(a) * head_w2[lane];
    }
    float o = wred_sum(hval);
    if (lane == 0) out[b] = o + head_b2[0];
}

// ---------------- launch ----------------
extern "C" void kernel_launch(void* const* d_in, const int* in_sizes, int n_in,
                              void* d_out, int out_size, void* d_ws, size_t ws_size,
                              hipStream_t stream) {
    (void)in_sizes; (void)n_in; (void)out_size; (void)ws_size;
    const float* x        = (const float*)d_in[0];
    const int*   ei       = (const int*)d_in[1];
    const float* fw       = (const float*)d_in[2];
    const float* fft_w1   = (const float*)d_in[3];
    const float* fft_b1   = (const float*)d_in[4];
    const float* fft_ln1g = (const float*)d_in[5];
    const float* fft_ln1b = (const float*)d_in[6];
    const float* fft_w2   = (const float*)d_in[7];
    const float* fft_b2   = (const float*)d_in[8];
    const float* fft_ln2g = (const float*)d_in[9];
    const float* fft_ln2b = (const float*)d_in[10];
    const float* ge_w     = (const float*)d_in[11];
    const float* ge_b     = (const float*)d_in[12];
    const float* ge_g     = (const float*)d_in[13];
    const float* ge_beta  = (const float*)d_in[14];
    const float* gat_w    = (const float*)d_in[15];
    const float* gat_attn = (const float*)d_in[16];
    const float* gp_w     = (const float*)d_in[17];
    const float* gp_b     = (const float*)d_in[18];
    const float* gp_ln_g  = (const float*)d_in[19];
    const float* gp_ln_b  = (const float*)d_in[20];
    const float* pl_W     = (const float*)d_in[21];
    const float* pl_alpha = (const float*)d_in[22];
    const float* pl_eta   = (const float*)d_in[23];
    const float* pl_bias  = (const float*)d_in[24];
    const float* pn_g     = (const float*)d_in[25];
    const float* pn_b     = (const float*)d_in[26];
    const float* pp_w     = (const float*)d_in[27];
    const float* pp_b     = (const float*)d_in[28];
    const float* pp_ln_g  = (const float*)d_in[29];
    const float* pp_ln_b  = (const float*)d_in[30];
    const float* gate_w1  = (const float*)d_in[31];
    const float* gate_b1  = (const float*)d_in[32];
    const float* gate_w2  = (const float*)d_in[33];
    const float* gate_b2  = (const float*)d_in[34];
    const float* head_w1  = (const float*)d_in[35];
    const float* head_b1  = (const float*)d_in[36];
    const float* head_w2  = (const float*)d_in[37];
    const float* head_b2  = (const float*)d_in[38];

    float* ws  = (float*)d_ws;
    float* out = (float*)d_out;

    // zero grid weights + edge counts (contiguous)
    hipMemsetAsync(ws + W_WEIGHT, 0, (BZ * NG + N_CPGS) * sizeof(float), stream);
    k_pre<<<6 + TTB + HB, 256, 0, stream>>>(x, ge_w, ge_b, ge_g, ge_beta,
                                            gat_w, gat_attn, fw, ei, ws);
    k_node<<<1 + NODEB + 400, 256, 0, stream>>>(x, ws);
    k_scat2<<<HB + 160 + H0MB, 256, 0, stream>>>(ei, ws);
    k_gatdots<<<DOTSB + GATB, 256, 0, stream>>>(fft_w1, pl_W, pl_alpha, fw, ws);
    k_final<<<1, 256, 0, stream>>>(fft_b1, fft_ln1g, fft_ln1b, fft_w2, fft_b2, fft_ln2g, fft_ln2b,
                                   gp_w, gp_b, gp_ln_g, gp_ln_b, pl_eta, pl_bias, pn_g, pn_b,
                                   pp_w, pp_b, pp_ln_g, pp_ln_b, gate_w1, gate_b1, gate_w2, gate_b2,
                                   head_w1, head_b1, head_w2, head_b2, ws, out);
}

// Round 13
// 207.782 us; speedup vs baseline: 1.0250x; 1.0250x over previous
//
#include <hip/hip_runtime.h>
#include <math.h>

// ---------------- problem constants ----------------
constexpr int N_CPGS = 20000;
constexpr int NF     = 10001;      // N/2+1
constexpr int BZ     = 4;
constexpr int NEDGE  = 320000;
constexpr int KPAD   = 10240;      // padded freq count
// FFT decomposition: n = n1 + 200*n2, n1 in [0,200), n2 in [0,100)
constexpr int FN1    = 200;
constexpr int FN2    = 100;
constexpr int HB     = NEDGE / 256;          // 1250 hist/scatter blocks
constexpr int DOTSB  = 384;                  // dots blocks (first in k_gatdots)
constexpr int GATB   = 4096;                 // GAT blocks
constexpr int NG     = 4096;                 // x-grid size (table)
constexpr int TROW   = 144;                  // table row stride (136 used, f4-pad)
constexpr int TTB    = NG / 64;              // 64 table-tile blocks
constexpr int APPB   = BZ * N_CPGS / 64;     // 1250 apply blocks (64 nodes each)
constexpr int H0MB   = 32;                   // h0sum matmul blocks

// ---------------- workspace layout (float offsets) ----------------
constexpr size_t W_XMEAN   = 0;        // 4
constexpr size_t W_SMSTAT  = 64;       // 2
constexpr size_t W_NORMSQ  = 128;      // 4   [zeroed in k_pre]
constexpr size_t W_H0SUM   = 192;      // 256 [zeroed in k_pre]
constexpr size_t W_GATMEAN = 448;      // 256 [zeroed in k_pre]
constexpr size_t W_PREP    = 704;      // 8
constexpr size_t W_D       = 768;      // 3*128*4
constexpr size_t W_MAG     = 2304;     // BZ*NF = 40004
constexpr size_t W_SSRC    = 42368;    // float[(b*N+n)*4+h] = 320000 (per-batch)
constexpr size_t W_SDST    = 362368;   // 320000
constexpr size_t W_H       = 682368;   // bf16[(b*N+n)*64+f] = 5.12MB (per-batch)
constexpr size_t W_Y       = 5802368;  // float2[(n1*100+k2)*4+b] = 160000 floats
constexpr size_t W_TAB     = 5962368;  // NG*TROW = 589824 floats (~2.36MB)
                                       // row: [0..63] h, [64..127] h0, [128..131] s_src, [132..135] s_dst
constexpr size_t W_WEIGHT  = 9062784;  // 4*4096 grid weights [zeroed via memset]
constexpr size_t W_COUNTS  = 9079168;  // int 20000 [zeroed via memset]
constexpr size_t W_OFFS    = 9099168;  // int 20001
constexpr size_t W_CURSOR  = 9119232;  // int 20000
constexpr size_t W_SORTSRC = 9139232;  // int 320000
// end: 9459232 floats = 37,836,928 bytes

#define DEVFN static __device__ __forceinline__

// Fast gelu: A&S 7.1.26 erf, |abs err| <= 1.5e-7.
DEVFN float gelu_f(float v) {
    float ax = fabsf(v) * 0.70710678118654752440f;
    float t = 1.0f / fmaf(0.3275911f, ax, 1.0f);
    float p = fmaf(t, 1.061405429f, -1.453152027f);
    p = fmaf(p, t, 1.421413741f);
    p = fmaf(p, t, -0.284496736f);
    p = fmaf(p, t, 0.254829592f);
    p = p * t;
    float e = __expf(-ax * ax);
    float er = copysignf(fmaf(-p, e, 1.0f), v);
    return 0.5f * v * (1.0f + er);
}

DEVFN float wred_sum(float v) {
    #pragma unroll
    for (int m = 32; m; m >>= 1) v += __shfl_xor(v, m);
    return v;
}

DEVFN unsigned int bfr(float f) {            // fp32 -> bf16 bits, RNE
    unsigned int u = __float_as_uint(f);
    return (u + 0x7fffu + ((u >> 16) & 1u)) >> 16;
}
DEVFN float bf2f(unsigned short v) { return __uint_as_float(((unsigned int)v) << 16); }

// ====== L1: k_pre — stats/zeroing (0-5) + table build (6-69) + edge histogram (70+) ======
__global__ __launch_bounds__(256) void k_pre(
    const float* __restrict__ x, const float* __restrict__ ge_w,
    const float* __restrict__ ge_b, const float* __restrict__ ge_g,
    const float* __restrict__ ge_beta, const float* __restrict__ gat_w,
    const float* __restrict__ gat_attn, const float* __restrict__ fw,
    const int* __restrict__ ei, float* __restrict__ ws) {
    int bb = blockIdx.x, t = threadIdx.x;
    if (bb >= 6 + TTB) {                               // edge histogram (counts pre-zeroed)
        int e = (bb - 6 - TTB) * 256 + t;
        if (e < NEDGE) atomicAdd((int*)(ws + W_COUNTS) + ei[NEDGE + e], 1);
        return;
    }
    if (bb >= 6) {
        // ---- table tile: 64 grid points x (h, h0, scores) ----
        int g0 = (bb - 6) * 64;
        int lane = t & 63;
        float wv_ = ge_w[lane], bv_ = ge_b[lane];
        float mw = wred_sum(wv_) * (1.f / 64.f);
        float mb = wred_sum(bv_) * (1.f / 64.f);
        float wc = wv_ - mw, bc = bv_ - mb;
        float A = wred_sum(wc * wc) * (1.f / 64.f);
        float C = wred_sum(wc * bc) * (1.f / 64.f);
        float Dd = wred_sum(bc * bc) * (1.f / 64.f);

        __shared__ __align__(16) float h0T[64 * 68];   // [feat j][gridpt]
        __shared__ __align__(16) float gwT[64 * 68];   // [j][i] = gat_w[i][j]
        __shared__ float xsv[64], rss[64];

        for (int idx = t; idx < 4096; idx += 256) {
            int i = idx >> 6, j = idx & 63;
            gwT[j * 68 + i] = gat_w[idx];
        }
        if (t < 64) {
            float xg = (float)(g0 + t) * (1.0f / 4095.0f);
            xsv[t] = xg;
            float var = xg * xg * A + 2.f * xg * C + Dd;
            rss[t] = 1.0f / sqrtf(var + 1e-5f);
        }
        __syncthreads();
        for (int idx = t; idx < 4096; idx += 256) {
            int j = idx >> 6, nd = idx & 63;
            float v = (xsv[nd] * (ge_w[j] - mw) + (ge_b[j] - mb)) * rss[nd];
            h0T[j * 68 + nd] = gelu_f(v * ge_g[j] + ge_beta[j]);
        }
        __syncthreads();
        // 64x64 @ 64x64 matmul, 16x16 threads, 4x4 micro-tile
        int tr = t >> 4, tc = t & 15;
        float acc[4][4] = {};
        #pragma unroll 8
        for (int j = 0; j < 64; ++j) {
            const float4 av = *(const float4*)&h0T[j * 68 + (tr << 2)];
            const float4 bv = *(const float4*)&gwT[j * 68 + (tc << 2)];
            #pragma unroll
            for (int u = 0; u < 4; ++u) {
                float a = (u == 0) ? av.x : (u == 1) ? av.y : (u == 2) ? av.z : av.w;
                acc[u][0] = fmaf(a, bv.x, acc[u][0]);
                acc[u][1] = fmaf(a, bv.y, acc[u][1]);
                acc[u][2] = fmaf(a, bv.z, acc[u][2]);
                acc[u][3] = fmaf(a, bv.w, acc[u][3]);
            }
        }
        float* tab = ws + W_TAB;
        #pragma unroll
        for (int u = 0; u < 4; ++u) {
            int gp = g0 + tr * 4 + u;
            *(float4*)&tab[(size_t)gp * TROW + tc * 4] =
                make_float4(acc[u][0], acc[u][1], acc[u][2], acc[u][3]);
        }
        for (int idx = t; idx < 4096; idx += 256) {
            int j = idx >> 6, nd = idx & 63;
            tab[(size_t)(g0 + nd) * TROW + 64 + j] = h0T[j * 68 + nd];
        }
        {
            int hh = tc >> 2;
            float ps[4], pd[4];
            #pragma unroll
            for (int u = 0; u < 4; ++u) {
                float s = 0.f, d = 0.f;
                #pragma unroll
                for (int kk = 0; kk < 4; ++kk) {
                    float asv = gat_attn[hh * 32 + (tc & 3) * 4 + kk];
                    float adv = gat_attn[hh * 32 + 16 + (tc & 3) * 4 + kk];
                    s = fmaf(acc[u][kk], asv, s);
                    d = fmaf(acc[u][kk], adv, d);
                }
                ps[u] = s; pd[u] = d;
            }
            #pragma unroll
            for (int u = 0; u < 4; ++u) {
                ps[u] += __shfl_xor(ps[u], 1); ps[u] += __shfl_xor(ps[u], 2);
                pd[u] += __shfl_xor(pd[u], 1); pd[u] += __shfl_xor(pd[u], 2);
            }
            if ((tc & 3) == 0) {
                #pragma unroll
                for (int u = 0; u < 4; ++u) {
                    int gp = g0 + tr * 4 + u;
                    tab[(size_t)gp * TROW + 128 + hh] = ps[u];
                    tab[(size_t)gp * TROW + 132 + hh] = pd[u];
                }
            }
        }
        return;
    }
    __shared__ float sd[256];
    if (bb < 4) {
        const float4* x4 = (const float4*)(x + (size_t)bb * N_CPGS);
        float s = 0.f;
        for (int i = t; i < N_CPGS / 4; i += 256) {
            float4 v = x4[i];
            s += (v.x + v.y) + (v.z + v.w);
        }
        sd[t] = s; __syncthreads();
        for (int o = 128; o; o >>= 1) { if (t < o) sd[t] += sd[t + o]; __syncthreads(); }
        if (t == 0) ws[W_XMEAN + bb] = sd[0] * (1.0f / N_CPGS);
    } else if (bb == 4) {
        for (int i = t; i < (int)(W_PREP - W_NORMSQ); i += 256) ws[W_NORMSQ + i] = 0.f;
    } else {    // bb == 5
        float mx = -1e30f;
        for (int i = t; i < NF; i += 256) mx = fmaxf(mx, fw[i]);
        sd[t] = mx; __syncthreads();
        for (int o = 128; o; o >>= 1) { if (t < o) sd[t] = fmaxf(sd[t], sd[t + o]); __syncthreads(); }
        mx = sd[0]; __syncthreads();
        float s = 0.f;
        for (int i = t; i < NF; i += 256) s += expf(fw[i] - mx);
        sd[t] = s; __syncthreads();
        for (int o = 128; o; o >>= 1) { if (t < o) sd[t] += sd[t + o]; __syncthreads(); }
        if (t == 0) { ws[W_SMSTAT] = mx; ws[W_SMSTAT + 1] = sd[0]; }
    }
}

// ====== L2: k_node — block 0: scan; [1,1+APPB): wave-coop table-apply; rest: fft1 ======
// Apply: lane = nl*16+tc; 16 lanes cover one node's 128B h-row -> coalesced 512B/wave store.
__global__ __launch_bounds__(256) void k_node(const float* __restrict__ x,
                                              float* __restrict__ ws)
{
    int t = threadIdx.x;
    int nb = blockIdx.x;
    if (nb == 0) {                                     // exclusive scan of dst counts
        const int* cnt = (const int*)(ws + W_COUNTS);
        int* offs = (int*)(ws + W_OFFS);
        int* cur  = (int*)(ws + W_CURSOR);
        constexpr int PER = (N_CPGS + 255) / 256;      // 79
        int i0 = t * PER;
        int s = 0;
        for (int i = 0; i < PER; ++i) { int idx = i0 + i; if (idx < N_CPGS) s += cnt[idx]; }
        __shared__ int sdi[256];
        sdi[t] = s; __syncthreads();
        for (int off = 1; off < 256; off <<= 1) {
            int v = (t >= off) ? sdi[t - off] : 0;
            __syncthreads();
            sdi[t] += v;
            __syncthreads();
        }
        int run = sdi[t] - s;
        for (int i = 0; i < PER; ++i) {
            int idx = i0 + i;
            if (idx < N_CPGS) { offs[idx] = run; cur[idx] = run; run += cnt[idx]; }
        }
        if (t == 255) offs[N_CPGS] = sdi[255];
        return;
    }
    if (nb >= 1 + APPB) {                              // FFT stage 1
        int fb = nb - 1 - APPB;                        // 0..399
        int b = fb / 100;
        int n1base = (fb % 100) * 2;
        int n1l = t >> 7, k2 = t & 127;
        __shared__ float xs[2][100];
        float xm = ws[W_XMEAN + b];
        for (int i = t; i < 200; i += 256) {
            int nl = (i >= 100) ? 1 : 0, n2 = (i >= 100) ? i - 100 : i;
            xs[nl][n2] = x[(size_t)b * N_CPGS + n1base + nl + 200 * n2] - xm;
        }
        __syncthreads();
        int k2e = (k2 < 100) ? k2 : 0;
        constexpr float T100 = 6.2831853071795864769f / 100.f;
        float dc, dsn;
        { float sn, cn; sincosf(T100 * (float)k2e, &sn, &cn); dc = cn; dsn = -sn; }
        float yr = 0.f, yi = 0.f;
        #pragma unroll
        for (int half = 0; half < 2; ++half) {
            float c, s;
            { int m = (k2e * (half * 50)) % 100; float sn, cn; sincosf(T100 * (float)m, &sn, &cn); c = cn; s = -sn; }
            #pragma unroll 5
            for (int j = 0; j < 50; ++j) {
                float xv = xs[n1l][half * 50 + j];
                yr = fmaf(xv, c, yr); yi = fmaf(xv, s, yi);
                float tc_ = c * dc - s * dsn; s = s * dc + c * dsn; c = tc_;
            }
        }
        if (k2 < 100)
            ((float2*)(ws + W_Y))[((size_t)(n1base + n1l) * FN2 + k2) * 4 + b] = make_float2(yr, yi);
        return;
    }
    // ---- wave-cooperative table apply ----
    int a = nb - 1;                                    // 0..1249
    int w = t >> 6, lane = t & 63;
    int nl = lane >> 4, tc = lane & 15;
    int m0 = a * 64 + w * 16;
    unsigned short* hbp = (unsigned short*)(ws + W_H);
    #pragma unroll
    for (int i = 0; i < 4; ++i) {
        int m = m0 + i * 4 + nl;                       // < 80000
        int b = m / N_CPGS;
        int n = m - b * N_CPGS;
        float xv = x[m];                               // x is [b][n] contiguous = flat m
        float u = xv * 4095.0f;
        int g = (int)u;
        g = (g < 0) ? 0 : ((g > 4094) ? 4094 : g);
        float f = u - (float)g;
        const float* T0 = ws + W_TAB + (size_t)g * TROW;
        const float* T1 = T0 + TROW;
        float4 av = *(const float4*)(T0 + tc * 4);
        float4 cv = *(const float4*)(T1 + tc * 4);
        uint2 pv;
        pv.x = bfr(fmaf(f, cv.x - av.x, av.x)) | (bfr(fmaf(f, cv.y - av.y, av.y)) << 16);
        pv.y = bfr(fmaf(f, cv.z - av.z, av.z)) | (bfr(fmaf(f, cv.w - av.w, av.w)) << 16);
        *(uint2*)(hbp + (size_t)m * 64 + tc * 4) = pv;
        if (tc < 4) {
            float a0 = T0[128 + tc], c0 = T1[128 + tc];
            ws[W_SSRC + (size_t)m * 4 + tc] = fmaf(f, c0 - a0, a0);
        } else if (tc < 8) {
            int hh = tc - 4;
            float a0 = T0[132 + hh], c0 = T1[132 + hh];
            ws[W_SDST + (size_t)m * 4 + hh] = fmaf(f, c0 - a0, a0);
        } else if (tc == 8) {
            atomicAdd(ws + W_WEIGHT + (size_t)b * NG + g, 1.0f - f);
        } else if (tc == 9) {
            atomicAdd(ws + W_WEIGHT + (size_t)b * NG + g + 1, f);
        }
    }
}

// == L3: k_scat2 — [0,HB): scatter; [HB,HB+160): fft2+mag+norms; [HB+160,+32): h0sum mm ==
__global__ __launch_bounds__(256) void k_scat2(const int* __restrict__ ei,
                                               float* __restrict__ ws) {
    int t = threadIdx.x;
    if (blockIdx.x < HB) {
        int e = blockIdx.x * 256 + t;
        if (e < NEDGE) {
            int s = ei[e], d = ei[NEDGE + e];
            int pos = atomicAdd((int*)(ws + W_CURSOR) + d, 1);
            ((int*)(ws + W_SORTSRC))[pos] = s;
        }
        return;
    }
    if (blockIdx.x >= HB + 160) {
        // h0sum[b][j] = sum_g weight[b][g] * T_h0[g][j]
        int hb = blockIdx.x - HB - 160;                // 0..31
        int b = t >> 6, j = t & 63;
        const float* wgt = ws + W_WEIGHT + (size_t)b * NG;
        const float* tab = ws + W_TAB;
        float acc = 0.f;
        int gbeg = hb * (NG / H0MB), gend = gbeg + NG / H0MB;
        for (int g = gbeg; g < gend; ++g)
            acc = fmaf(wgt[g], tab[(size_t)g * TROW + 64 + j], acc);
        atomicAdd(ws + W_H0SUM + b * 64 + j, acc);
        return;
    }
    // FFT stage 2, full 200-term sum per thread: gid -> (k, b)
    int gid = (blockIdx.x - HB) * 256 + t;             // 0..40959
    int k = gid >> 2, b = gid & 3;                     // k < KPAD
    int k2 = k % 100;
    const float2* Y2 = (const float2*)(ws + W_Y);
    constexpr float W0 = 6.2831853071795864769f / 20000.f;
    float dc, dsn;
    { float sn, cn; sincosf(W0 * (float)k, &sn, &cn); dc = cn; dsn = -sn; }
    float xr = 0.f, xi = 0.f;
    #pragma unroll
    for (int seg = 0; seg < 4; ++seg) {
        int n1b = seg * 50;
        float c, s;
        { int m = (k * n1b) % 20000; float sn, cn; sincosf(W0 * (float)m, &sn, &cn); c = cn; s = -sn; }
        #pragma unroll 5
        for (int j = 0; j < 50; ++j) {
            float2 y = Y2[((size_t)(n1b + j) * FN2 + k2) * 4 + b];
            xr = fmaf(y.x, c, xr); xr = fmaf(-y.y, s, xr);
            xi = fmaf(y.x, s, xi); xi = fmaf( y.y, c, xi);
            float tc_ = c * dc - s * dsn; s = s * dc + c * dsn; c = tc_;
        }
    }
    bool ok = k < NF;
    float m = 0.f;
    if (ok) {
        m = log1pf(sqrtf(xr * xr + xi * xi));
        ws[W_MAG + (size_t)b * NF + k] = m;
    }
    float msq = ok ? m * m : 0.f;
    #pragma unroll
    for (int o = 4; o < 64; o <<= 1) msq += __shfl_xor(msq, o);   // sum over same-b lanes
    if ((t & 63) < 4) atomicAdd(ws + W_NORMSQ + b, msq);
}

// ======== L4: k_gatdots — [0,DOTSB): dots; [DOTSB,DOTSB+GATB): GAT ====
__global__ __launch_bounds__(256) void k_gatdots(
    const float* __restrict__ fftw1, const float* __restrict__ plW,
    const float* __restrict__ plalpha, const float* __restrict__ fw,
    float* __restrict__ ws)
{
    int t = threadIdx.x;
    if (blockIdx.x >= DOTSB) {
        int g = blockIdx.x - DOTSB;                    // 0..4095
        int xcd = g & 7;
        int b = xcd >> 1;                              // batch pinned to 2 XCDs
        int blk = ((g >> 3) << 1) | (xcd & 1);         // 0..1023
        int w = t >> 6, lane = t & 63;
        int wv = blk * 4 + w;                          // 0..4095
        int egrp = lane >> 4, fgrp = lane & 15;
        int hh = fgrp >> 2;
        const int* offs = (const int*)(ws + W_OFFS);
        const int* ssrt = (const int*)(ws + W_SORTSRC);
        const float4* s4src = (const float4*)(ws + W_SSRC);
        const float4* s4dst = (const float4*)(ws + W_SDST);
        const uint2* hbp = (const uint2*)(ws + W_H);
        size_t bN = (size_t)b * N_CPGS;
        float gacc0 = 0.f, gacc1 = 0.f, gacc2 = 0.f, gacc3 = 0.f;

        __shared__ float elds[4][4][68];               // [wave][head][edge]
        __shared__ int   slds[4][68];
        __shared__ float gred[4][64];

        for (int dst = wv; dst < N_CPGS; dst += GATB) {
            int o0 = offs[dst], o1 = offs[dst + 1];
            if (o0 == o1) continue;                    // gelu(0) = 0
            float4 sd4 = s4dst[bN + dst];
            float es = 0.f;
            float a0 = 0.f, a1 = 0.f, a2 = 0.f, a3 = 0.f;
            for (int c0 = o0; c0 < o1; c0 += 64) {
                int cnt = min(64, o1 - c0);
                float v0 = 0.f, v1 = 0.f, v2 = 0.f, v3 = 0.f;
                int s = 0;
                if (lane < cnt) {
                    s = ssrt[c0 + lane];
                    float4 ss = s4src[bN + s];
                    v0 = ss.x + sd4.x; v0 = (v0 >= 0.f) ? v0 : 0.2f * v0; v0 = __expf(v0);
                    v1 = ss.y + sd4.y; v1 = (v1 >= 0.f) ? v1 : 0.2f * v1; v1 = __expf(v1);
                    v2 = ss.z + sd4.z; v2 = (v2 >= 0.f) ? v2 : 0.2f * v2; v2 = __expf(v2);
                    v3 = ss.w + sd4.w; v3 = (v3 >= 0.f) ? v3 : 0.2f * v3; v3 = __expf(v3);
                }
                slds[w][lane] = s;
                elds[w][0][lane] = v0; elds[w][1][lane] = v1;
                elds[w][2][lane] = v2; elds[w][3][lane] = v3;
                int niter = (cnt + 3) >> 2;
                for (int i = 0; i < niter; ++i) {
                    int j = (i << 2) + egrp;
                    float e = elds[w][hh][j];
                    int sj = slds[w][j];
                    uint2 hv = hbp[(bN + sj) * 16 + fgrp];
                    es += e;
                    a0 = fmaf(e, bf2f((unsigned short)(hv.x & 0xffffu)), a0);
                    a1 = fmaf(e, bf2f((unsigned short)(hv.x >> 16)),     a1);
                    a2 = fmaf(e, bf2f((unsigned short)(hv.y & 0xffffu)), a2);
                    a3 = fmaf(e, bf2f((unsigned short)(hv.y >> 16)),     a3);
                }
            }
            es += __shfl_xor(es, 16); es += __shfl_xor(es, 32);
            a0 += __shfl_xor(a0, 16); a0 += __shfl_xor(a0, 32);
            a1 += __shfl_xor(a1, 16); a1 += __shfl_xor(a1, 32);
            a2 += __shfl_xor(a2, 16); a2 += __shfl_xor(a2, 32);
            a3 += __shfl_xor(a3, 16); a3 += __shfl_xor(a3, 32);
            float inv = 1.f / (es + 1e-8f);
            gacc0 += gelu_f(a0 * inv); gacc1 += gelu_f(a1 * inv);
            gacc2 += gelu_f(a2 * inv); gacc3 += gelu_f(a3 * inv);
        }
        if (egrp == 0) {
            gred[w][fgrp * 4 + 0] = gacc0; gred[w][fgrp * 4 + 1] = gacc1;
            gred[w][fgrp * 4 + 2] = gacc2; gred[w][fgrp * 4 + 3] = gacc3;
        }
        __syncthreads();
        if (t < 64)
            atomicAdd(ws + W_GATMEAN + b * 64 + t, gred[0][t] + gred[1][t] + gred[2][t] + gred[3][t]);
        return;
    }
    // ---- dots (blocks 0..383) ----
    int bb2 = blockIdx.x;
    int m = bb2 >> 7;
    int r = bb2 & 127;
    const float* mag = ws + W_MAG;
    float smx = ws[W_SMSTAT], ssm = ws[W_SMSTAT + 1];
    float sc_fw = (float)NF / ssm;
    float inv_n0 = 1.f / (sqrtf(ws[W_NORMSQ + 0]) + 1e-8f);
    float inv_n1 = 1.f / (sqrtf(ws[W_NORMSQ + 1]) + 1e-8f);
    float inv_n2 = 1.f / (sqrtf(ws[W_NORMSQ + 2]) + 1e-8f);
    float inv_n3 = 1.f / (sqrtf(ws[W_NORMSQ + 3]) + 1e-8f);
    const float* row = ((m == 0) ? fftw1 : (m == 1) ? plW : plalpha) + (size_t)r * NF;
    float a0 = 0.f, a1 = 0.f, a2 = 0.f, a3 = 0.f;
    for (int k = t; k < NF; k += 256) {
        float wv = row[k];
        float g0 = mag[k], g1 = mag[NF + k], g2 = mag[2 * NF + k], g3 = mag[3 * NF + k];
        if (m == 0) {
            float s = expf(fw[k] - smx) * sc_fw;
            wv *= s;
            a0 = fmaf(wv, g0, a0); a1 = fmaf(wv, g1, a1); a2 = fmaf(wv, g2, a2); a3 = fmaf(wv, g3, a3);
        } else if (m == 1) {
            a0 = fmaf(wv, g0, a0); a1 = fmaf(wv, g1, a1); a2 = fmaf(wv, g2, a2); a3 = fmaf(wv, g3, a3);
        } else {
            wv = 1.f / (1.f + expf(-wv));   // sigmoid(pl_alpha)
            a0 = fmaf(wv, g0 * g0 * inv_n0, a0); a1 = fmaf(wv, g1 * g1 * inv_n1, a1);
            a2 = fmaf(wv, g2 * g2 * inv_n2, a2); a3 = fmaf(wv, g3 * g3 * inv_n3, a3);
        }
    }
    __shared__ float sd[256];
    float acc[4] = {a0, a1, a2, a3};
    #pragma unroll
    for (int bb = 0; bb < 4; ++bb) {
        sd[t] = acc[bb]; __syncthreads();
        for (int o = 128; o; o >>= 1) { if (t < o) sd[t] += sd[t + o]; __syncthreads(); }
        if (t == 0) ws[W_D + ((size_t)m * 128 + r) * 4 + bb] = sd[0];
        __syncthreads();
    }
}

// ================= L5: k_final =================
DEVFN float ln64(float v, const float* g, const float* bt, int lane) {
    float mn = wred_sum(v) * (1.f / 64.f);
    float d = v - mn;
    float var = wred_sum(d * d) * (1.f / 64.f);
    return d * (1.0f / sqrtf(var + 1e-5f)) * g[lane] + bt[lane];
}
DEVFN void ln128(float& v0, float& v1, const float* g, const float* bt, int lane) {
    float mn = wred_sum(v0 + v1) * (1.f / 128.f);
    float d0 = v0 - mn, d1 = v1 - mn;
    float var = wred_sum(d0 * d0 + d1 * d1) * (1.f / 128.f);
    float rs = 1.0f / sqrtf(var + 1e-5f);
    v0 = d0 * rs * g[lane] + bt[lane];
    v1 = d1 * rs * g[lane + 64] + bt[lane + 64];
}
DEVFN float dotW128(const float* __restrict__ W, const float* __restrict__ v, int c) {
    const float4* w4 = (const float4*)(W + (size_t)c * 128);
    float acc = 0.f;
    #pragma unroll
    for (int q = 0; q < 32; ++q) {
        float4 wv = w4[q];
        const float* vv = v + q * 4;
        acc = fmaf(wv.x, vv[0], acc); acc = fmaf(wv.y, vv[1], acc);
        acc = fmaf(wv.z, vv[2], acc); acc = fmaf(wv.w, vv[3], acc);
    }
    return acc;
}
DEVFN float dotW64(const float* __restrict__ W, const float* __restrict__ v, int c) {
    const float4* w4 = (const float4*)(W + (size_t)c * 64);
    float acc = 0.f;
    #pragma unroll
    for (int q = 0; q < 16; ++q) {
        float4 wv = w4[q];
        const float* vv = v + q * 4;
        acc = fmaf(wv.x, vv[0], acc); acc = fmaf(wv.y, vv[1], acc);
        acc = fmaf(wv.z, vv[2], acc); acc = fmaf(wv.w, vv[3], acc);
    }
    return acc;
}

__global__ __launch_bounds__(256) void k_final(
    const float* __restrict__ fft_b1, const float* __restrict__ fft_ln1_g, const float* __restrict__ fft_ln1_b,
    const float* __restrict__ fft_w2, const float* __restrict__ fft_b2,
    const float* __restrict__ fft_ln2_g, const float* __restrict__ fft_ln2_b,
    const float* __restrict__ gp_w, const float* __restrict__ gp_b,
    const float* __restrict__ gp_ln_g, const float* __restrict__ gp_ln_b,
    const float* __restrict__ pl_eta, const float* __restrict__ pl_bias,
    const float* __restrict__ pn_g, const float* __restrict__ pn_b,
    const float* __restrict__ pp_w, const float* __restrict__ pp_b,
    const float* __restrict__ pp_ln_g, const float* __restrict__ pp_ln_b,
    const float* __restrict__ gate_w1, const float* __restrict__ gate_b1,
    const float* __restrict__ gate_w2, const float* __restrict__ gate_b2,
    const float* __restrict__ head_w1, const float* __restrict__ head_b1,
    const float* __restrict__ head_w2, const float* __restrict__ head_b2,
    float* __restrict__ ws, float* __restrict__ out)
{
    int t = threadIdx.x, b = t >> 6, lane = t & 63;
    __shared__ float vlds[4][256];
    float* vb = vlds[b];
    const float* D = ws + W_D;
    int r0 = lane, r1 = lane + 64;

    float f0 = D[(0 * 128 + r0) * 4 + b] + fft_b1[r0];
    float f1 = D[(0 * 128 + r1) * 4 + b] + fft_b1[r1];
    ln128(f0, f1, fft_ln1_g, fft_ln1_b, lane);
    vb[lane] = gelu_f(f0); vb[64 + lane] = gelu_f(f1);
    float catf = ln64(dotW128(fft_w2, vb, lane) + fft_b2[lane], fft_ln2_g, fft_ln2_b, lane);

    float hgm = (ws[W_H0SUM + b * 64 + lane] + ws[W_GATMEAN + b * 64 + lane]) * (1.f / N_CPGS);
    vb[lane] = hgm;
    float catg = ln64(dotW64(gp_w, vb, lane) + gp_b[lane], gp_ln_g, gp_ln_b, lane);

    float eta = pl_eta[0];
    float ys0 = D[(1 * 128 + r0) * 4 + b] + pl_bias[r0];
    float ys1 = D[(1 * 128 + r1) * 4 + b] + pl_bias[r1];
    float q0 = D[(2 * 128 + r0) * 4 + b];
    float q1 = D[(2 * 128 + r1) * 4 + b];
    float u0 = gelu_f(ys0 + eta * tanhf(ys0) * q0);
    float u1 = gelu_f(ys1 + eta * tanhf(ys1) * q1);
    ln128(u0, u1, pn_g, pn_b, lane);
    vb[lane] = u0; vb[64 + lane] = u1;
    float catp = ln64(dotW128(pp_w, vb, lane) + pp_b[lane], pp_ln_g, pp_ln_b, lane);

    vb[lane] = catf; vb[64 + lane] = catg; vb[128 + lane] = catp;
    if (lane < 6) {
        float a = gate_b1[lane];
        const float* wrow = gate_w1 + lane * 192;
        #pragma unroll 4
        for (int j = 0; j < 192; ++j) a = fmaf(wrow[j], vb[j], a);
        vb[192 + lane] = gelu_f(a);
    }
    float gv[3];
    #pragma unroll
    for (int c = 0; c < 3; ++c) {
        float a = gate_b2[c];
        #pragma unroll
        for (int j = 0; j < 6; ++j) a = fmaf(gate_w2[c * 6 + j], vb[192 + j], a);
        gv[c] = a;
    }
    float gmx = fmaxf(gv[0], fmaxf(gv[1], gv[2]));
    float e0 = expf(gv[0] - gmx), e1 = expf(gv[1] - gmx), e2 = expf(gv[2] - gmx);
    float inv = 1.f / (e0 + e1 + e2);
    float fus = catf * (e0 * inv) + catg * (e1 * inv) + catp * (e2 * inv);

    vb[lane] = fus;
    float hval = 0.f;
    if (lane < 32) {
        float a = dotW64(head_w1, vb, lane) + head_b1[lane];
        hval = gelu_f(a) * head_w2[lane];
    }
    float o = wred_sum(hval);
    if (lane == 0) out[b] = o + head_b2[0];
}

// ---------------- launch ----------------
extern "C" void kernel_launch(void* const* d_in, const int* in_sizes, int n_in,
                              void* d_out, int out_size, void* d_ws, size_t ws_size,
                              hipStream_t stream) {
    (void)in_sizes; (void)n_in; (void)out_size; (void)ws_size;
    const float* x        = (const float*)d_in[0];
    const int*   ei       = (const int*)d_in[1];
    const float* fw       = (const float*)d_in[2];
    const float* fft_w1   = (const float*)d_in[3];
    const float* fft_b1   = (const float*)d_in[4];
    const float* fft_ln1g = (const float*)d_in[5];
    const float* fft_ln1b = (const float*)d_in[6];
    const float* fft_w2   = (const float*)d_in[7];
    const float* fft_b2   = (const float*)d_in[8];
    const float* fft_ln2g = (const float*)d_in[9];
    const float* fft_ln2b = (const float*)d_in[10];
    const float* ge_w     = (const float*)d_in[11];
    const float* ge_b     = (const float*)d_in[12];
    const float* ge_g     = (const float*)d_in[13];
    const float* ge_beta  = (const float*)d_in[14];
    const float* gat_w    = (const float*)d_in[15];
    const float* gat_attn = (const float*)d_in[16];
    const float* gp_w     = (const float*)d_in[17];
    const float* gp_b     = (const float*)d_in[18];
    const float* gp_ln_g  = (const float*)d_in[19];
    const float* gp_ln_b  = (const float*)d_in[20];
    const float* pl_W     = (const float*)d_in[21];
    const float* pl_alpha = (const float*)d_in[22];
    const float* pl_eta   = (const float*)d_in[23];
    const float* pl_bias  = (const float*)d_in[24];
    const float* pn_g     = (const float*)d_in[25];
    const float* pn_b     = (const float*)d_in[26];
    const float* pp_w     = (const float*)d_in[27];
    const float* pp_b     = (const float*)d_in[28];
    const float* pp_ln_g  = (const float*)d_in[29];
    const float* pp_ln_b  = (const float*)d_in[30];
    const float* gate_w1  = (const float*)d_in[31];
    const float* gate_b1  = (const float*)d_in[32];
    const float* gate_w2  = (const float*)d_in[33];
    const float* gate_b2  = (const float*)d_in[34];
    const float* head_w1  = (const float*)d_in[35];
    const float* head_b1  = (const float*)d_in[36];
    const float* head_w2  = (const float*)d_in[37];
    const float* head_b2  = (const float*)d_in[38];

    float* ws  = (float*)d_ws;
    float* out = (float*)d_out;

    // zero grid weights + edge counts (contiguous)
    hipMemsetAsync(ws + W_WEIGHT, 0, (BZ * NG + N_CPGS) * sizeof(float), stream);
    k_pre<<<6 + TTB + HB, 256, 0, stream>>>(x, ge_w, ge_b, ge_g, ge_beta,
                                            gat_w, gat_attn, fw, ei, ws);
    k_node<<<1 + APPB + 400, 256, 0, stream>>>(x, ws);
    k_scat2<<<HB + 160 + H0MB, 256, 0, stream>>>(ei, ws);
    k_gatdots<<<DOTSB + GATB, 256, 0, stream>>>(fft_w1, pl_W, pl_alpha, fw, ws);
    k_final<<<1, 256, 0, stream>>>(fft_b1, fft_ln1g, fft_ln1b, fft_w2, fft_b2, fft_ln2g, fft_ln2b,
                                   gp_w, gp_b, gp_ln_g, gp_ln_b, pl_eta, pl_bias, pn_g, pn_b,
                                   pp_w, pp_b, pp_ln_g, pp_ln_b, gate_w1, gate_b1, gate_w2, gate_b2,
                                   head_w1, head_b1, head_w2, head_b2, ws, out);
}

// Round 14
// 182.338 us; speedup vs baseline: 1.1680x; 1.1395x over previous
//
#include <hip/hip_runtime.h>
#include <math.h>

// ---------------- problem constants ----------------
constexpr int N_CPGS = 20000;
constexpr int NF     = 10001;      // N/2+1
constexpr int BZ     = 4;
constexpr int NEDGE  = 320000;
constexpr int KPAD   = 10240;      // padded freq count
// FFT decomposition: n = n1 + 200*n2, n1 in [0,200), n2 in [0,100)
constexpr int FN1    = 200;
constexpr int FN2    = 100;
constexpr int HB     = NEDGE / 256;          // 1250 hist/scatter blocks
constexpr int DOTSB  = 384;                  // dots blocks (first in k_gatdots)
constexpr int GATB   = 4096;                 // GAT blocks
constexpr int NG     = 4096;                 // x-grid size (table)
constexpr int TROW   = 144;                  // table row stride (136 used, f4-pad)
constexpr int TTB    = NG / 64;              // 64 table-tile blocks
constexpr int APPB   = BZ * N_CPGS / 64;     // 1250 apply blocks (64 nodes each)
constexpr int H0MB   = 32;                   // h0sum matmul blocks

// ---------------- workspace layout (float offsets) ----------------
constexpr size_t W_XMEAN   = 0;        // 4
constexpr size_t W_SMSTAT  = 64;       // 2
constexpr size_t W_NORMSQ  = 128;      // 4   [zeroed in k_pre]
constexpr size_t W_H0SUM   = 192;      // 256 [zeroed in k_pre]
constexpr size_t W_GATMEAN = 448;      // 256 [zeroed in k_pre]
constexpr size_t W_PREP    = 704;      // 8
constexpr size_t W_D       = 768;      // 3*128*4
constexpr size_t W_MAG     = 2304;     // BZ*NF = 40004
constexpr size_t W_SSRC    = 42368;    // float[(b*N+n)*4+h] = 320000 (per-batch)
constexpr size_t W_SDST    = 362368;   // 320000
constexpr size_t W_H       = 682368;   // bf16[(b*N+n)*64+f] = 5.12MB (per-batch)
constexpr size_t W_Y       = 5802368;  // float2[(n1*100+k2)*4+b] = 160000 floats
constexpr size_t W_TAB     = 5962368;  // NG*TROW = 589824 floats (~2.36MB)
                                       // row: [0..63] h, [64..127] h0, [128..131] s_src, [132..135] s_dst
constexpr size_t W_WEIGHT  = 9062784;  // 4*4096 grid weights [zeroed via memset]
constexpr size_t W_COUNTS  = 9079168;  // int 20000 [zeroed via memset]
constexpr size_t W_OFFS    = 9099168;  // int 20001
constexpr size_t W_CURSOR  = 9119232;  // int 20000
constexpr size_t W_SORTSRC = 9139232;  // int 320000
// end: 9459232 floats = 37,836,928 bytes

#define DEVFN static __device__ __forceinline__

// Fast gelu: A&S 7.1.26 erf, |abs err| <= 1.5e-7.
DEVFN float gelu_f(float v) {
    float ax = fabsf(v) * 0.70710678118654752440f;
    float t = 1.0f / fmaf(0.3275911f, ax, 1.0f);
    float p = fmaf(t, 1.061405429f, -1.453152027f);
    p = fmaf(p, t, 1.421413741f);
    p = fmaf(p, t, -0.284496736f);
    p = fmaf(p, t, 0.254829592f);
    p = p * t;
    float e = __expf(-ax * ax);
    float er = copysignf(fmaf(-p, e, 1.0f), v);
    return 0.5f * v * (1.0f + er);
}

DEVFN float wred_sum(float v) {
    #pragma unroll
    for (int m = 32; m; m >>= 1) v += __shfl_xor(v, m);
    return v;
}

DEVFN unsigned int bfr(float f) {            // fp32 -> bf16 bits, RNE
    unsigned int u = __float_as_uint(f);
    return (u + 0x7fffu + ((u >> 16) & 1u)) >> 16;
}
DEVFN float bf2f(unsigned short v) { return __uint_as_float(((unsigned int)v) << 16); }

// ====== L1: k_pre — stats/zeroing (0-5) + table build (6-69) + edge histogram (70+) ======
__global__ __launch_bounds__(256) void k_pre(
    const float* __restrict__ x, const float* __restrict__ ge_w,
    const float* __restrict__ ge_b, const float* __restrict__ ge_g,
    const float* __restrict__ ge_beta, const float* __restrict__ gat_w,
    const float* __restrict__ gat_attn, const float* __restrict__ fw,
    const int* __restrict__ ei, float* __restrict__ ws) {
    int bb = blockIdx.x, t = threadIdx.x;
    if (bb >= 6 + TTB) {                               // edge histogram (counts pre-zeroed)
        int e = (bb - 6 - TTB) * 256 + t;
        if (e < NEDGE) atomicAdd((int*)(ws + W_COUNTS) + ei[NEDGE + e], 1);
        return;
    }
    if (bb >= 6) {
        // ---- table tile: 64 grid points x (h, h0, scores) ----
        int g0 = (bb - 6) * 64;
        int lane = t & 63;
        float wv_ = ge_w[lane], bv_ = ge_b[lane];
        float mw = wred_sum(wv_) * (1.f / 64.f);
        float mb = wred_sum(bv_) * (1.f / 64.f);
        float wc = wv_ - mw, bc = bv_ - mb;
        float A = wred_sum(wc * wc) * (1.f / 64.f);
        float C = wred_sum(wc * bc) * (1.f / 64.f);
        float Dd = wred_sum(bc * bc) * (1.f / 64.f);

        __shared__ __align__(16) float h0T[64 * 68];   // [feat j][gridpt]
        __shared__ __align__(16) float gwT[64 * 68];   // [j][i] = gat_w[i][j]
        __shared__ float xsv[64], rss[64];

        for (int idx = t; idx < 4096; idx += 256) {
            int i = idx >> 6, j = idx & 63;
            gwT[j * 68 + i] = gat_w[idx];
        }
        if (t < 64) {
            float xg = (float)(g0 + t) * (1.0f / 4095.0f);
            xsv[t] = xg;
            float var = xg * xg * A + 2.f * xg * C + Dd;
            rss[t] = 1.0f / sqrtf(var + 1e-5f);
        }
        __syncthreads();
        for (int idx = t; idx < 4096; idx += 256) {
            int j = idx >> 6, nd = idx & 63;
            float v = (xsv[nd] * (ge_w[j] - mw) + (ge_b[j] - mb)) * rss[nd];
            h0T[j * 68 + nd] = gelu_f(v * ge_g[j] + ge_beta[j]);
        }
        __syncthreads();
        // 64x64 @ 64x64 matmul, 16x16 threads, 4x4 micro-tile
        int tr = t >> 4, tc = t & 15;
        float acc[4][4] = {};
        #pragma unroll 8
        for (int j = 0; j < 64; ++j) {
            const float4 av = *(const float4*)&h0T[j * 68 + (tr << 2)];
            const float4 bv = *(const float4*)&gwT[j * 68 + (tc << 2)];
            #pragma unroll
            for (int u = 0; u < 4; ++u) {
                float a = (u == 0) ? av.x : (u == 1) ? av.y : (u == 2) ? av.z : av.w;
                acc[u][0] = fmaf(a, bv.x, acc[u][0]);
                acc[u][1] = fmaf(a, bv.y, acc[u][1]);
                acc[u][2] = fmaf(a, bv.z, acc[u][2]);
                acc[u][3] = fmaf(a, bv.w, acc[u][3]);
            }
        }
        float* tab = ws + W_TAB;
        #pragma unroll
        for (int u = 0; u < 4; ++u) {
            int gp = g0 + tr * 4 + u;
            *(float4*)&tab[(size_t)gp * TROW + tc * 4] =
                make_float4(acc[u][0], acc[u][1], acc[u][2], acc[u][3]);
        }
        for (int idx = t; idx < 4096; idx += 256) {
            int j = idx >> 6, nd = idx & 63;
            tab[(size_t)(g0 + nd) * TROW + 64 + j] = h0T[j * 68 + nd];
        }
        {
            int hh = tc >> 2;
            float ps[4], pd[4];
            #pragma unroll
            for (int u = 0; u < 4; ++u) {
                float s = 0.f, d = 0.f;
                #pragma unroll
                for (int kk = 0; kk < 4; ++kk) {
                    float asv = gat_attn[hh * 32 + (tc & 3) * 4 + kk];
                    float adv = gat_attn[hh * 32 + 16 + (tc & 3) * 4 + kk];
                    s = fmaf(acc[u][kk], asv, s);
                    d = fmaf(acc[u][kk], adv, d);
                }
                ps[u] = s; pd[u] = d;
            }
            #pragma unroll
            for (int u = 0; u < 4; ++u) {
                ps[u] += __shfl_xor(ps[u], 1); ps[u] += __shfl_xor(ps[u], 2);
                pd[u] += __shfl_xor(pd[u], 1); pd[u] += __shfl_xor(pd[u], 2);
            }
            if ((tc & 3) == 0) {
                #pragma unroll
                for (int u = 0; u < 4; ++u) {
                    int gp = g0 + tr * 4 + u;
                    tab[(size_t)gp * TROW + 128 + hh] = ps[u];
                    tab[(size_t)gp * TROW + 132 + hh] = pd[u];
                }
            }
        }
        return;
    }
    __shared__ float sd[256];
    if (bb < 4) {
        const float4* x4 = (const float4*)(x + (size_t)bb * N_CPGS);
        float s = 0.f;
        for (int i = t; i < N_CPGS / 4; i += 256) {
            float4 v = x4[i];
            s += (v.x + v.y) + (v.z + v.w);
        }
        sd[t] = s; __syncthreads();
        for (int o = 128; o; o >>= 1) { if (t < o) sd[t] += sd[t + o]; __syncthreads(); }
        if (t == 0) ws[W_XMEAN + bb] = sd[0] * (1.0f / N_CPGS);
    } else if (bb == 4) {
        for (int i = t; i < (int)(W_PREP - W_NORMSQ); i += 256) ws[W_NORMSQ + i] = 0.f;
    } else {    // bb == 5
        float mx = -1e30f;
        for (int i = t; i < NF; i += 256) mx = fmaxf(mx, fw[i]);
        sd[t] = mx; __syncthreads();
        for (int o = 128; o; o >>= 1) { if (t < o) sd[t] = fmaxf(sd[t], sd[t + o]); __syncthreads(); }
        mx = sd[0]; __syncthreads();
        float s = 0.f;
        for (int i = t; i < NF; i += 256) s += expf(fw[i] - mx);
        sd[t] = s; __syncthreads();
        for (int o = 128; o; o >>= 1) { if (t < o) sd[t] += sd[t + o]; __syncthreads(); }
        if (t == 0) { ws[W_SMSTAT] = mx; ws[W_SMSTAT + 1] = sd[0]; }
    }
}

// ====== k_scan — single 1024-thread block, register-cached counts (no serial reloads) ======
__global__ __launch_bounds__(1024) void k_scan(float* __restrict__ ws) {
    int t = threadIdx.x;
    const int* cnt = (const int*)(ws + W_COUNTS);
    int* offs = (int*)(ws + W_OFFS);
    int* cur  = (int*)(ws + W_CURSOR);
    int i0 = t * 20;
    int v[20];
    #pragma unroll
    for (int q = 0; q < 5; ++q) {
        int idx = i0 + q * 4;
        int4 c4;
        if (idx + 3 < N_CPGS) {
            c4 = *(const int4*)(cnt + idx);
        } else {
            c4.x = (idx + 0 < N_CPGS) ? cnt[idx + 0] : 0;
            c4.y = (idx + 1 < N_CPGS) ? cnt[idx + 1] : 0;
            c4.z = (idx + 2 < N_CPGS) ? cnt[idx + 2] : 0;
            c4.w = (idx + 3 < N_CPGS) ? cnt[idx + 3] : 0;
        }
        v[q * 4 + 0] = c4.x; v[q * 4 + 1] = c4.y;
        v[q * 4 + 2] = c4.z; v[q * 4 + 3] = c4.w;
    }
    int s = 0;
    #pragma unroll
    for (int q = 0; q < 20; ++q) s += v[q];
    __shared__ int sd[1024];
    sd[t] = s; __syncthreads();
    for (int off = 1; off < 1024; off <<= 1) {
        int vv = (t >= off) ? sd[t - off] : 0;
        __syncthreads();
        sd[t] += vv;
        __syncthreads();
    }
    int run = sd[t] - s;   // exclusive prefix
    #pragma unroll
    for (int q = 0; q < 20; ++q) {
        int idx = i0 + q;
        if (idx < N_CPGS) { offs[idx] = run; cur[idx] = run; run += v[q]; }
    }
    if (t == 1023) offs[N_CPGS] = sd[1023];
}

// ====== L2: k_node — [0,APPB): wave-coop table-apply; [APPB,APPB+400): FFT stage 1 ======
__global__ __launch_bounds__(256) void k_node(const float* __restrict__ x,
                                              float* __restrict__ ws)
{
    int t = threadIdx.x;
    int nb = blockIdx.x;
    if (nb >= APPB) {                                  // FFT stage 1
        int fb = nb - APPB;                            // 0..399
        int b = fb / 100;
        int n1base = (fb % 100) * 2;
        int n1l = t >> 7, k2 = t & 127;
        __shared__ float xs[2][100];
        float xm = ws[W_XMEAN + b];
        for (int i = t; i < 200; i += 256) {
            int nl = (i >= 100) ? 1 : 0, n2 = (i >= 100) ? i - 100 : i;
            xs[nl][n2] = x[(size_t)b * N_CPGS + n1base + nl + 200 * n2] - xm;
        }
        __syncthreads();
        int k2e = (k2 < 100) ? k2 : 0;
        constexpr float T100 = 6.2831853071795864769f / 100.f;
        float dc, dsn;
        { float sn, cn; sincosf(T100 * (float)k2e, &sn, &cn); dc = cn; dsn = -sn; }
        float yr = 0.f, yi = 0.f;
        #pragma unroll
        for (int half = 0; half < 2; ++half) {
            float c, s;
            { int m = (k2e * (half * 50)) % 100; float sn, cn; sincosf(T100 * (float)m, &sn, &cn); c = cn; s = -sn; }
            #pragma unroll 5
            for (int j = 0; j < 50; ++j) {
                float xv = xs[n1l][half * 50 + j];
                yr = fmaf(xv, c, yr); yi = fmaf(xv, s, yi);
                float tc_ = c * dc - s * dsn; s = s * dc + c * dsn; c = tc_;
            }
        }
        if (k2 < 100)
            ((float2*)(ws + W_Y))[((size_t)(n1base + n1l) * FN2 + k2) * 4 + b] = make_float2(yr, yi);
        return;
    }
    // ---- wave-cooperative table apply ----
    int a = nb;                                        // 0..1249
    int w = t >> 6, lane = t & 63;
    int nl = lane >> 4, tc = lane & 15;
    int m0 = a * 64 + w * 16;
    unsigned short* hbp = (unsigned short*)(ws + W_H);
    #pragma unroll
    for (int i = 0; i < 4; ++i) {
        int m = m0 + i * 4 + nl;                       // < 80000
        int b = m / N_CPGS;
        float xv = x[m];                               // x is [b][n] contiguous = flat m
        float u = xv * 4095.0f;
        int g = (int)u;
        g = (g < 0) ? 0 : ((g > 4094) ? 4094 : g);
        float f = u - (float)g;
        const float* T0 = ws + W_TAB + (size_t)g * TROW;
        const float* T1 = T0 + TROW;
        float4 av = *(const float4*)(T0 + tc * 4);
        float4 cv = *(const float4*)(T1 + tc * 4);
        uint2 pv;
        pv.x = bfr(fmaf(f, cv.x - av.x, av.x)) | (bfr(fmaf(f, cv.y - av.y, av.y)) << 16);
        pv.y = bfr(fmaf(f, cv.z - av.z, av.z)) | (bfr(fmaf(f, cv.w - av.w, av.w)) << 16);
        *(uint2*)(hbp + (size_t)m * 64 + tc * 4) = pv;
        if (tc < 4) {
            float a0 = T0[128 + tc], c0 = T1[128 + tc];
            ws[W_SSRC + (size_t)m * 4 + tc] = fmaf(f, c0 - a0, a0);
        } else if (tc < 8) {
            int hh = tc - 4;
            float a0 = T0[132 + hh], c0 = T1[132 + hh];
            ws[W_SDST + (size_t)m * 4 + hh] = fmaf(f, c0 - a0, a0);
        } else if (tc == 8) {
            atomicAdd(ws + W_WEIGHT + (size_t)b * NG + g, 1.0f - f);
        } else if (tc == 9) {
            atomicAdd(ws + W_WEIGHT + (size_t)b * NG + g + 1, f);
        }
    }
}

// == L3: k_scat2 — [0,HB): scatter; [HB,HB+160): fft2+mag+norms; [HB+160,+32): h0sum mm ==
__global__ __launch_bounds__(256) void k_scat2(const int* __restrict__ ei,
                                               float* __restrict__ ws) {
    int t = threadIdx.x;
    if (blockIdx.x < HB) {
        int e = blockIdx.x * 256 + t;
        if (e < NEDGE) {
            int s = ei[e], d = ei[NEDGE + e];
            int pos = atomicAdd((int*)(ws + W_CURSOR) + d, 1);
            ((int*)(ws + W_SORTSRC))[pos] = s;
        }
        return;
    }
    if (blockIdx.x >= HB + 160) {
        // h0sum[b][j] = sum_g weight[b][g] * T_h0[g][j]
        int hb = blockIdx.x - HB - 160;                // 0..31
        int b = t >> 6, j = t & 63;
        const float* wgt = ws + W_WEIGHT + (size_t)b * NG;
        const float* tab = ws + W_TAB;
        float acc = 0.f;
        int gbeg = hb * (NG / H0MB), gend = gbeg + NG / H0MB;
        for (int g = gbeg; g < gend; ++g)
            acc = fmaf(wgt[g], tab[(size_t)g * TROW + 64 + j], acc);
        atomicAdd(ws + W_H0SUM + b * 64 + j, acc);
        return;
    }
    // FFT stage 2, full 200-term sum per thread: gid -> (k, b)
    int gid = (blockIdx.x - HB) * 256 + t;             // 0..40959
    int k = gid >> 2, b = gid & 3;                     // k < KPAD
    int k2 = k % 100;
    const float2* Y2 = (const float2*)(ws + W_Y);
    constexpr float W0 = 6.2831853071795864769f / 20000.f;
    float dc, dsn;
    { float sn, cn; sincosf(W0 * (float)k, &sn, &cn); dc = cn; dsn = -sn; }
    float xr = 0.f, xi = 0.f;
    #pragma unroll
    for (int seg = 0; seg < 4; ++seg) {
        int n1b = seg * 50;
        float c, s;
        { int m = (k * n1b) % 20000; float sn, cn; sincosf(W0 * (float)m, &sn, &cn); c = cn; s = -sn; }
        #pragma unroll 5
        for (int j = 0; j < 50; ++j) {
            float2 y = Y2[((size_t)(n1b + j) * FN2 + k2) * 4 + b];
            xr = fmaf(y.x, c, xr); xr = fmaf(-y.y, s, xr);
            xi = fmaf(y.x, s, xi); xi = fmaf( y.y, c, xi);
            float tc_ = c * dc - s * dsn; s = s * dc + c * dsn; c = tc_;
        }
    }
    bool ok = k < NF;
    float m = 0.f;
    if (ok) {
        m = log1pf(sqrtf(xr * xr + xi * xi));
        ws[W_MAG + (size_t)b * NF + k] = m;
    }
    float msq = ok ? m * m : 0.f;
    #pragma unroll
    for (int o = 4; o < 64; o <<= 1) msq += __shfl_xor(msq, o);   // sum over same-b lanes
    if ((t & 63) < 4) atomicAdd(ws + W_NORMSQ + b, msq);
}

// ======== L4: k_gatdots — [0,DOTSB): dots; [DOTSB,DOTSB+GATB): GAT ====
__global__ __launch_bounds__(256) void k_gatdots(
    const float* __restrict__ fftw1, const float* __restrict__ plW,
    const float* __restrict__ plalpha, const float* __restrict__ fw,
    float* __restrict__ ws)
{
    int t = threadIdx.x;
    if (blockIdx.x >= DOTSB) {
        int g = blockIdx.x - DOTSB;                    // 0..4095
        int xcd = g & 7;
        int b = xcd >> 1;                              // batch pinned to 2 XCDs
        int blk = ((g >> 3) << 1) | (xcd & 1);         // 0..1023
        int w = t >> 6, lane = t & 63;
        int wv = blk * 4 + w;                          // 0..4095
        int egrp = lane >> 4, fgrp = lane & 15;
        int hh = fgrp >> 2;
        const int* offs = (const int*)(ws + W_OFFS);
        const int* ssrt = (const int*)(ws + W_SORTSRC);
        const float4* s4src = (const float4*)(ws + W_SSRC);
        const float4* s4dst = (const float4*)(ws + W_SDST);
        const uint2* hbp = (const uint2*)(ws + W_H);
        size_t bN = (size_t)b * N_CPGS;
        float gacc0 = 0.f, gacc1 = 0.f, gacc2 = 0.f, gacc3 = 0.f;

        __shared__ float elds[4][4][68];               // [wave][head][edge]
        __shared__ int   slds[4][68];
        __shared__ float gred[4][64];

        for (int dst = wv; dst < N_CPGS; dst += GATB) {
            int o0 = offs[dst], o1 = offs[dst + 1];
            if (o0 == o1) continue;                    // gelu(0) = 0
            float4 sd4 = s4dst[bN + dst];
            float es = 0.f;
            float a0 = 0.f, a1 = 0.f, a2 = 0.f, a3 = 0.f;
            for (int c0 = o0; c0 < o1; c0 += 64) {
                int cnt = min(64, o1 - c0);
                float v0 = 0.f, v1 = 0.f, v2 = 0.f, v3 = 0.f;
                int s = 0;
                if (lane < cnt) {
                    s = ssrt[c0 + lane];
                    float4 ss = s4src[bN + s];
                    v0 = ss.x + sd4.x; v0 = (v0 >= 0.f) ? v0 : 0.2f * v0; v0 = __expf(v0);
                    v1 = ss.y + sd4.y; v1 = (v1 >= 0.f) ? v1 : 0.2f * v1; v1 = __expf(v1);
                    v2 = ss.z + sd4.z; v2 = (v2 >= 0.f) ? v2 : 0.2f * v2; v2 = __expf(v2);
                    v3 = ss.w + sd4.w; v3 = (v3 >= 0.f) ? v3 : 0.2f * v3; v3 = __expf(v3);
                }
                slds[w][lane] = s;
                elds[w][0][lane] = v0; elds[w][1][lane] = v1;
                elds[w][2][lane] = v2; elds[w][3][lane] = v3;
                int niter = (cnt + 3) >> 2;
                for (int i = 0; i < niter; ++i) {
                    int j = (i << 2) + egrp;
                    float e = elds[w][hh][j];
                    int sj = slds[w][j];
                    uint2 hv = hbp[(bN + sj) * 16 + fgrp];
                    es += e;
                    a0 = fmaf(e, bf2f((unsigned short)(hv.x & 0xffffu)), a0);
                    a1 = fmaf(e, bf2f((unsigned short)(hv.x >> 16)),     a1);
                    a2 = fmaf(e, bf2f((unsigned short)(hv.y & 0xffffu)), a2);
                    a3 = fmaf(e, bf2f((unsigned short)(hv.y >> 16)),     a3);
                }
            }
            es += __shfl_xor(es, 16); es += __shfl_xor(es, 32);
            a0 += __shfl_xor(a0, 16); a0 += __shfl_xor(a0, 32);
            a1 += __shfl_xor(a1, 16); a1 += __shfl_xor(a1, 32);
            a2 += __shfl_xor(a2, 16); a2 += __shfl_xor(a2, 32);
            a3 += __shfl_xor(a3, 16); a3 += __shfl_xor(a3, 32);
            float inv = 1.f / (es + 1e-8f);
            gacc0 += gelu_f(a0 * inv); gacc1 += gelu_f(a1 * inv);
            gacc2 += gelu_f(a2 * inv); gacc3 += gelu_f(a3 * inv);
        }
        if (egrp == 0) {
            gred[w][fgrp * 4 + 0] = gacc0; gred[w][fgrp * 4 + 1] = gacc1;
            gred[w][fgrp * 4 + 2] = gacc2; gred[w][fgrp * 4 + 3] = gacc3;
        }
        __syncthreads();
        if (t < 64)
            atomicAdd(ws + W_GATMEAN + b * 64 + t, gred[0][t] + gred[1][t] + gred[2][t] + gred[3][t]);
        return;
    }
    // ---- dots (blocks 0..383) ----
    int bb2 = blockIdx.x;
    int m = bb2 >> 7;
    int r = bb2 & 127;
    const float* mag = ws + W_MAG;
    float smx = ws[W_SMSTAT], ssm = ws[W_SMSTAT + 1];
    float sc_fw = (float)NF / ssm;
    float inv_n0 = 1.f / (sqrtf(ws[W_NORMSQ + 0]) + 1e-8f);
    float inv_n1 = 1.f / (sqrtf(ws[W_NORMSQ + 1]) + 1e-8f);
    float inv_n2 = 1.f / (sqrtf(ws[W_NORMSQ + 2]) + 1e-8f);
    float inv_n3 = 1.f / (sqrtf(ws[W_NORMSQ + 3]) + 1e-8f);
    const float* row = ((m == 0) ? fftw1 : (m == 1) ? plW : plalpha) + (size_t)r * NF;
    float a0 = 0.f, a1 = 0.f, a2 = 0.f, a3 = 0.f;
    for (int k = t; k < NF; k += 256) {
        float wv = row[k];
        float g0 = mag[k], g1 = mag[NF + k], g2 = mag[2 * NF + k], g3 = mag[3 * NF + k];
        if (m == 0) {
            float s = expf(fw[k] - smx) * sc_fw;
            wv *= s;
            a0 = fmaf(wv, g0, a0); a1 = fmaf(wv, g1, a1); a2 = fmaf(wv, g2, a2); a3 = fmaf(wv, g3, a3);
        } else if (m == 1) {
            a0 = fmaf(wv, g0, a0); a1 = fmaf(wv, g1, a1); a2 = fmaf(wv, g2, a2); a3 = fmaf(wv, g3, a3);
        } else {
            wv = 1.f / (1.f + expf(-wv));   // sigmoid(pl_alpha)
            a0 = fmaf(wv, g0 * g0 * inv_n0, a0); a1 = fmaf(wv, g1 * g1 * inv_n1, a1);
            a2 = fmaf(wv, g2 * g2 * inv_n2, a2); a3 = fmaf(wv, g3 * g3 * inv_n3, a3);
        }
    }
    __shared__ float sd[256];
    float acc[4] = {a0, a1, a2, a3};
    #pragma unroll
    for (int bb = 0; bb < 4; ++bb) {
        sd[t] = acc[bb]; __syncthreads();
        for (int o = 128; o; o >>= 1) { if (t < o) sd[t] += sd[t + o]; __syncthreads(); }
        if (t == 0) ws[W_D + ((size_t)m * 128 + r) * 4 + bb] = sd[0];
        __syncthreads();
    }
}

// ================= L5: k_final =================
DEVFN float ln64(float v, const float* g, const float* bt, int lane) {
    float mn = wred_sum(v) * (1.f / 64.f);
    float d = v - mn;
    float var = wred_sum(d * d) * (1.f / 64.f);
    return d * (1.0f / sqrtf(var + 1e-5f)) * g[lane] + bt[lane];
}
DEVFN void ln128(float& v0, float& v1, const float* g, const float* bt, int lane) {
    float mn = wred_sum(v0 + v1) * (1.f / 128.f);
    float d0 = v0 - mn, d1 = v1 - mn;
    float var = wred_sum(d0 * d0 + d1 * d1) * (1.f / 128.f);
    float rs = 1.0f / sqrtf(var + 1e-5f);
    v0 = d0 * rs * g[lane] + bt[lane];
    v1 = d1 * rs * g[lane + 64] + bt[lane + 64];
}
DEVFN float dotW128(const float* __restrict__ W, const float* __restrict__ v, int c) {
    const float4* w4 = (const float4*)(W + (size_t)c * 128);
    float acc = 0.f;
    #pragma unroll
    for (int q = 0; q < 32; ++q) {
        float4 wv = w4[q];
        const float* vv = v + q * 4;
        acc = fmaf(wv.x, vv[0], acc); acc = fmaf(wv.y, vv[1], acc);
        acc = fmaf(wv.z, vv[2], acc); acc = fmaf(wv.w, vv[3], acc);
    }
    return acc;
}
DEVFN float dotW64(const float* __restrict__ W, const float* __restrict__ v, int c) {
    const float4* w4 = (const float4*)(W + (size_t)c * 64);
    float acc = 0.f;
    #pragma unroll
    for (int q = 0; q < 16; ++q) {
        float4 wv = w4[q];
        const float* vv = v + q * 4;
        acc = fmaf(wv.x, vv[0], acc); acc = fmaf(wv.y, vv[1], acc);
        acc = fmaf(wv.z, vv[2], acc); acc = fmaf(wv.w, vv[3], acc);
    }
    return acc;
}

__global__ __launch_bounds__(256) void k_final(
    const float* __restrict__ fft_b1, const float* __restrict__ fft_ln1_g, const float* __restrict__ fft_ln1_b,
    const float* __restrict__ fft_w2, const float* __restrict__ fft_b2,
    const float* __restrict__ fft_ln2_g, const float* __restrict__ fft_ln2_b,
    const float* __restrict__ gp_w, const float* __restrict__ gp_b,
    const float* __restrict__ gp_ln_g, const float* __restrict__ gp_ln_b,
    const float* __restrict__ pl_eta, const float* __restrict__ pl_bias,
    const float* __restrict__ pn_g, const float* __restrict__ pn_b,
    const float* __restrict__ pp_w, const float* __restrict__ pp_b,
    const float* __restrict__ pp_ln_g, const float* __restrict__ pp_ln_b,
    const float* __restrict__ gate_w1, const float* __restrict__ gate_b1,
    const float* __restrict__ gate_w2, const float* __restrict__ gate_b2,
    const float* __restrict__ head_w1, const float* __restrict__ head_b1,
    const float* __restrict__ head_w2, const float* __restrict__ head_b2,
    float* __restrict__ ws, float* __restrict__ out)
{
    int t = threadIdx.x, b = t >> 6, lane = t & 63;
    __shared__ float vlds[4][256];
    float* vb = vlds[b];
    const float* D = ws + W_D;
    int r0 = lane, r1 = lane + 64;

    float f0 = D[(0 * 128 + r0) * 4 + b] + fft_b1[r0];
    float f1 = D[(0 * 128 + r1) * 4 + b] + fft_b1[r1];
    ln128(f0, f1, fft_ln1_g, fft_ln1_b, lane);
    vb[lane] = gelu_f(f0); vb[64 + lane] = gelu_f(f1);
    float catf = ln64(dotW128(fft_w2, vb, lane) + fft_b2[lane], fft_ln2_g, fft_ln2_b, lane);

    float hgm = (ws[W_H0SUM + b * 64 + lane] + ws[W_GATMEAN + b * 64 + lane]) * (1.f / N_CPGS);
    vb[lane] = hgm;
    float catg = ln64(dotW64(gp_w, vb, lane) + gp_b[lane], gp_ln_g, gp_ln_b, lane);

    float eta = pl_eta[0];
    float ys0 = D[(1 * 128 + r0) * 4 + b] + pl_bias[r0];
    float ys1 = D[(1 * 128 + r1) * 4 + b] + pl_bias[r1];
    float q0 = D[(2 * 128 + r0) * 4 + b];
    float q1 = D[(2 * 128 + r1) * 4 + b];
    float u0 = gelu_f(ys0 + eta * tanhf(ys0) * q0);
    float u1 = gelu_f(ys1 + eta * tanhf(ys1) * q1);
    ln128(u0, u1, pn_g, pn_b, lane);
    vb[lane] = u0; vb[64 + lane] = u1;
    float catp = ln64(dotW128(pp_w, vb, lane) + pp_b[lane], pp_ln_g, pp_ln_b, lane);

    vb[lane] = catf; vb[64 + lane] = catg; vb[128 + lane] = catp;
    if (lane < 6) {
        float a = gate_b1[lane];
        const float* wrow = gate_w1 + lane * 192;
        #pragma unroll 4
        for (int j = 0; j < 192; ++j) a = fmaf(wrow[j], vb[j], a);
        vb[192 + lane] = gelu_f(a);
    }
    float gv[3];
    #pragma unroll
    for (int c = 0; c < 3; ++c) {
        float a = gate_b2[c];
        #pragma unroll
        for (int j = 0; j < 6; ++j) a = fmaf(gate_w2[c * 6 + j], vb[192 + j], a);
        gv[c] = a;
    }
    float gmx = fmaxf(gv[0], fmaxf(gv[1], gv[2]));
    float e0 = expf(gv[0] - gmx), e1 = expf(gv[1] - gmx), e2 = expf(gv[2] - gmx);
    float inv = 1.f / (e0 + e1 + e2);
    float fus = catf * (e0 * inv) + catg * (e1 * inv) + catp * (e2 * inv);

    vb[lane] = fus;
    float hval = 0.f;
    if (lane < 32) {
        float a = dotW64(head_w1, vb, lane) + head_b1[lane];
        hval = gelu_f(a) * head_w2[lane];
    }
    float o = wred_sum(hval);
    if (lane == 0) out[b] = o + head_b2[0];
}

// ---------------- launch ----------------
extern "C" void kernel_launch(void* const* d_in, const int* in_sizes, int n_in,
                              void* d_out, int out_size, void* d_ws, size_t ws_size,
                              hipStream_t stream) {
    (void)in_sizes; (void)n_in; (void)out_size; (void)ws_size;
    const float* x        = (const float*)d_in[0];
    const int*   ei       = (const int*)d_in[1];
    const float* fw       = (const float*)d_in[2];
    const float* fft_w1   = (const float*)d_in[3];
    const float* fft_b1   = (const float*)d_in[4];
    const float* fft_ln1g = (const float*)d_in[5];
    const float* fft_ln1b = (const float*)d_in[6];
    const float* fft_w2   = (const float*)d_in[7];
    const float* fft_b2   = (const float*)d_in[8];
    const float* fft_ln2g = (const float*)d_in[9];
    const float* fft_ln2b = (const float*)d_in[10];
    const float* ge_w     = (const float*)d_in[11];
    const float* ge_b     = (const float*)d_in[12];
    const float* ge_g     = (const float*)d_in[13];
    const float* ge_beta  = (const float*)d_in[14];
    const float* gat_w    = (const float*)d_in[15];
    const float* gat_attn = (const float*)d_in[16];
    const float* gp_w     = (const float*)d_in[17];
    const float* gp_b     = (const float*)d_in[18];
    const float* gp_ln_g  = (const float*)d_in[19];
    const float* gp_ln_b  = (const float*)d_in[20];
    const float* pl_W     = (const float*)d_in[21];
    const float* pl_alpha = (const float*)d_in[22];
    const float* pl_eta   = (const float*)d_in[23];
    const float* pl_bias  = (const float*)d_in[24];
    const float* pn_g     = (const float*)d_in[25];
    const float* pn_b     = (const float*)d_in[26];
    const float* pp_w     = (const float*)d_in[27];
    const float* pp_b     = (const float*)d_in[28];
    const float* pp_ln_g  = (const float*)d_in[29];
    const float* pp_ln_b  = (const float*)d_in[30];
    const float* gate_w1  = (const float*)d_in[31];
    const float* gate_b1  = (const float*)d_in[32];
    const float* gate_w2  = (const float*)d_in[33];
    const float* gate_b2  = (const float*)d_in[34];
    const float* head_w1  = (const float*)d_in[35];
    const float* head_b1  = (const float*)d_in[36];
    const float* head_w2  = (const float*)d_in[37];
    const float* head_b2  = (const float*)d_in[38];

    float* ws  = (float*)d_ws;
    float* out = (float*)d_out;

    // zero grid weights + edge counts (contiguous)
    hipMemsetAsync(ws + W_WEIGHT, 0, (BZ * NG + N_CPGS) * sizeof(float), stream);
    k_pre<<<6 + TTB + HB, 256, 0, stream>>>(x, ge_w, ge_b, ge_g, ge_beta,
                                            gat_w, gat_attn, fw, ei, ws);
    k_scan<<<1, 1024, 0, stream>>>(ws);
    k_node<<<APPB + 400, 256, 0, stream>>>(x, ws);
    k_scat2<<<HB + 160 + H0MB, 256, 0, stream>>>(ei, ws);
    k_gatdots<<<DOTSB + GATB, 256, 0, stream>>>(fft_w1, pl_W, pl_alpha, fw, ws);
    k_final<<<1, 256, 0, stream>>>(fft_b1, fft_ln1g, fft_ln1b, fft_w2, fft_b2, fft_ln2g, fft_ln2b,
                                   gp_w, gp_b, gp_ln_g, gp_ln_b, pl_eta, pl_bias, pn_g, pn_b,
                                   pp_w, pp_b, pp_ln_g, pp_ln_b, gate_w1, gate_b1, gate_w2, gate_b2,
                                   head_w1, head_b1, head_w2, head_b2, ws, out);
}